// Round 1
// baseline (1235.584 us; speedup 1.0000x reference)
//
#include <hip/hip_runtime.h>
#include <hip/hip_bf16.h>
#include <cstdio>

namespace {

constexpr int kSeq = 2048;
constexpr int kDModel = 2048;
constexpr int kHeads = 16;
constexpr int kDk = 128;
constexpr int kBatch = 2;
constexpr int kM = kBatch * kSeq;  // 4096 rows of x
constexpr float kQScale = 0.08838834764831845f;  // 1/sqrt(128)

typedef __bf16 bf16_t;
typedef __bf16 bf16x8 __attribute__((ext_vector_type(8)));
typedef __bf16 bf16x4 __attribute__((ext_vector_type(4)));
typedef float f32x4 __attribute__((ext_vector_type(4)));
typedef short s16x4 __attribute__((ext_vector_type(4)));

__device__ __forceinline__ f32x4 mfma32(bf16x8 a, bf16x8 b, f32x4 c) {
  return __builtin_amdgcn_mfma_f32_16x16x32_bf16(a, b, c, 0, 0, 0);
}

#if __has_builtin(__builtin_amdgcn_mfma_f32_16x16x16_bf16)
__device__ __forceinline__ f32x4 mfma16(bf16x4 a, bf16x4 b, f32x4 c) {
  return __builtin_amdgcn_mfma_f32_16x16x16_bf16(a, b, c, 0, 0, 0);
}
#else
__device__ __forceinline__ f32x4 mfma16(bf16x4 a, bf16x4 b, f32x4 c) {
  union U { bf16x4 b; s16x4 s; } ua, ub;
  ua.b = a; ub.b = b;
  return __builtin_amdgcn_mfma_f32_16x16x16bf16_1k(ua.s, ub.s, c, 0, 0, 0);
}
#endif

using gas_void = const __attribute__((address_space(1))) void;
using las_void = __attribute__((address_space(3))) void;

__device__ __forceinline__ void gload_lds16(const bf16_t* g, bf16_t* l) {
  __builtin_amdgcn_global_load_lds((gas_void*)g, (las_void*)l, 16, 0, 0);
}

// ---------------- RoPE table (fp64 for max fidelity vs np reference) --------
__global__ void k_rope_table(float* __restrict__ cost, float* __restrict__ sint) {
  const int p = blockIdx.x;
  const int i = threadIdx.x;
  const double inv = exp(-(double)(2 * i) * 9.210340371976184 / 128.0);
  const double ang = (double)p * inv;
  cost[p * 64 + i] = (float)cos(ang);
  sint[p * 64 + i] = (float)sin(ang);
}

// ---------------- x -> (hi,lo) bf16 split -----------------------------------
__global__ void k_split_x(const float* __restrict__ x, bf16_t* __restrict__ xh,
                          bf16_t* __restrict__ xl, int n) {
  const int idx = (blockIdx.x * blockDim.x + threadIdx.x) * 4;
  if (idx >= n) return;
  const float4 v = *(const float4*)(x + idx);
  const float vv[4] = {v.x, v.y, v.z, v.w};
  bf16x4 hv, lv;
#pragma unroll
  for (int j = 0; j < 4; ++j) {
    const bf16_t h = (bf16_t)vv[j];
    hv[j] = h;
    lv[j] = (bf16_t)(vv[j] - (float)h);
  }
  *(bf16x4*)(xh + idx) = hv;
  *(bf16x4*)(xl + idx) = lv;
}

// ---------------- W (fp32 [K][N]) -> W^T bf16 hi(/lo) [N][K] ----------------
__global__ void k_transpose_w(const float* __restrict__ w, bf16_t* __restrict__ wth,
                              bf16_t* __restrict__ wtl) {
  __shared__ float tile[32][33];
  const int bx = blockIdx.x * 32;  // n
  const int by = blockIdx.y * 32;  // k
  const int tx = threadIdx.x, ty = threadIdx.y;
#pragma unroll
  for (int i = 0; i < 32; i += 8)
    tile[ty + i][tx] = w[(size_t)(by + ty + i) * kDModel + bx + tx];
  __syncthreads();
#pragma unroll
  for (int i = 0; i < 32; i += 8) {
    const float v = tile[tx][ty + i];
    const size_t o = (size_t)(bx + ty + i) * kDModel + by + tx;
    const bf16_t h = (bf16_t)v;
    wth[o] = h;
    if (wtl) wtl[o] = (bf16_t)(v - (float)h);
  }
}

// ---------------- Tiled MFMA GEMM: C = A @ B (B given transposed [N][K]) ----
// TERMS==3: C = Ah*Bh + Ah*Bl + Al*Bh (split-bf16 ~fp32 accuracy)
// EPI: 0 = store fp32 row-major; 1 = RoPE + split-bf16 store (Q/K);
//      2 = store bf16 V^T per head [bh*128+d][s]
template <int TERMS, int EPI>
__global__ __launch_bounds__(256) void k_gemm(
    const bf16_t* __restrict__ Ah, const bf16_t* __restrict__ Al,
    const bf16_t* __restrict__ Bh, const bf16_t* __restrict__ Bl,
    void* __restrict__ O0, void* __restrict__ O1,
    const int* __restrict__ tokpos, const float* __restrict__ cost,
    const float* __restrict__ sint, float scale, int M, int N, int K) {
  __shared__ __align__(16) bf16_t sAh[128 * 32];
  __shared__ __align__(16) bf16_t sBh[128 * 32];
  __shared__ __align__(16) bf16_t sAl[TERMS == 3 ? 128 * 32 : 8];
  __shared__ __align__(16) bf16_t sBl[TERMS == 3 ? 128 * 32 : 8];

  const int tid = threadIdx.x;
  const int wid = tid >> 6;
  const int lane = tid & 63;
  const int lo = lane & 15, hi = lane >> 4;
  const int wr = wid >> 1, wc = wid & 1;
  const int m0 = blockIdx.y * 128, n0 = blockIdx.x * 128;

  f32x4 acc[4][4];
  const f32x4 z = {0.f, 0.f, 0.f, 0.f};
#pragma unroll
  for (int i = 0; i < 4; ++i)
#pragma unroll
    for (int j = 0; j < 4; ++j) acc[i][j] = z;

  const int rr = wid * 16 + (lane >> 2);  // staging row (chunk 0)
  const int kk = (lane & 3) * 8;          // staging k offset

  for (int k0 = 0; k0 < K; k0 += 32) {
    __syncthreads();
    {
      const bf16_t* gA = Ah + (size_t)(m0 + rr) * K + k0 + kk;
      gload_lds16(gA, sAh + wid * 512);
      gload_lds16(gA + (size_t)64 * K, sAh + 2048 + wid * 512);
      const bf16_t* gB = Bh + (size_t)(n0 + rr) * K + k0 + kk;
      gload_lds16(gB, sBh + wid * 512);
      gload_lds16(gB + (size_t)64 * K, sBh + 2048 + wid * 512);
      if constexpr (TERMS == 3) {
        const bf16_t* gAl = Al + (size_t)(m0 + rr) * K + k0 + kk;
        gload_lds16(gAl, sAl + wid * 512);
        gload_lds16(gAl + (size_t)64 * K, sAl + 2048 + wid * 512);
        const bf16_t* gBl = Bl + (size_t)(n0 + rr) * K + k0 + kk;
        gload_lds16(gBl, sBl + wid * 512);
        gload_lds16(gBl + (size_t)64 * K, sBl + 2048 + wid * 512);
      }
    }
    __syncthreads();
    bf16x8 fah[4], fbh[4];
#pragma unroll
    for (int mi = 0; mi < 4; ++mi)
      fah[mi] = *(const bf16x8*)(sAh + (wr * 64 + mi * 16 + lo) * 32 + 8 * hi);
#pragma unroll
    for (int ni = 0; ni < 4; ++ni)
      fbh[ni] = *(const bf16x8*)(sBh + (wc * 64 + ni * 16 + lo) * 32 + 8 * hi);
    if constexpr (TERMS == 3) {
      bf16x8 fal[4], fbl[4];
#pragma unroll
      for (int mi = 0; mi < 4; ++mi)
        fal[mi] = *(const bf16x8*)(sAl + (wr * 64 + mi * 16 + lo) * 32 + 8 * hi);
#pragma unroll
      for (int ni = 0; ni < 4; ++ni)
        fbl[ni] = *(const bf16x8*)(sBl + (wc * 64 + ni * 16 + lo) * 32 + 8 * hi);
#pragma unroll
      for (int mi = 0; mi < 4; ++mi)
#pragma unroll
        for (int ni = 0; ni < 4; ++ni) {
          acc[mi][ni] = mfma32(fah[mi], fbh[ni], acc[mi][ni]);
          acc[mi][ni] = mfma32(fah[mi], fbl[ni], acc[mi][ni]);
          acc[mi][ni] = mfma32(fal[mi], fbh[ni], acc[mi][ni]);
        }
    } else {
#pragma unroll
      for (int mi = 0; mi < 4; ++mi)
#pragma unroll
        for (int ni = 0; ni < 4; ++ni)
          acc[mi][ni] = mfma32(fah[mi], fbh[ni], acc[mi][ni]);
    }
  }

  if constexpr (EPI == 0) {
    float* C = (float*)O0;
#pragma unroll
    for (int mi = 0; mi < 4; ++mi)
#pragma unroll
      for (int ni = 0; ni < 4; ++ni)
#pragma unroll
        for (int r = 0; r < 4; ++r) {
          const int row = m0 + wr * 64 + mi * 16 + hi * 4 + r;
          const int col = n0 + wc * 64 + ni * 16 + lo;
          C[(size_t)row * N + col] = acc[mi][ni][r];
        }
  } else if constexpr (EPI == 1) {
    bf16_t* Xh = (bf16_t*)O0;
    bf16_t* Xl = (bf16_t*)O1;
    const int is64 = (tokpos[1] == 0) ? 1 : 0;  // int64 positions -> high word 0
#pragma unroll
    for (int mi = 0; mi < 4; ++mi) {
#pragma unroll
      for (int r = 0; r < 4; ++r) {
        const int row = m0 + wr * 64 + mi * 16 + hi * 4 + r;
        const int pos = is64 ? tokpos[2 * row] : tokpos[row];
#pragma unroll
        for (int ni = 0; ni < 4; ++ni) {
          const int col = n0 + wc * 64 + ni * 16 + lo;
          const float v = acc[mi][ni][r] * scale;
          const float pv = __shfl_xor(v, 1);  // paired column (col^1)
          const int ip = (col & 127) >> 1;
          const float c = cost[pos * 64 + ip];
          const float sn = sint[pos * 64 + ip];
          const float sgn = (lo & 1) ? sn : -sn;  // even: -x_o*s ; odd: +x_e*s
          const float rv = v * c + pv * sgn;
          const bf16_t hb = (bf16_t)rv;
          const size_t o = (size_t)row * N + col;
          Xh[o] = hb;
          Xl[o] = (bf16_t)(rv - (float)hb);
        }
      }
    }
  } else {  // EPI == 2 : V^T
    bf16_t* VT = (bf16_t*)O0;
#pragma unroll
    for (int mi = 0; mi < 4; ++mi)
#pragma unroll
      for (int ni = 0; ni < 4; ++ni) {
        const int col = n0 + wc * 64 + ni * 16 + lo;
        const int h = col >> 7, d = col & 127;
        const int rowb = m0 + wr * 64 + mi * 16 + hi * 4;
        const int b = rowb >> 11, s = rowb & (kSeq - 1);
        bf16x4 ov;
#pragma unroll
        for (int r = 0; r < 4; ++r) ov[r] = (bf16_t)acc[mi][ni][r];
        *(bf16x4*)(VT + ((size_t)((b * kHeads + h) * kDk + d)) * kSeq + s) = ov;
      }
  }
}

// ---------------- Causal flash attention ------------------------------------
// Swapped QK^T: ST[key][q] = mfma(A=K, B=Q)  (both operands k-contiguous).
// Softmax per q = per lane column; stats reduce via shfl_xor(16|32).
// PV: O^T[d][q] = mfma16(A=V^T, B=P^T) — P^T C-fragment feeds B-operand directly.
__global__ __launch_bounds__(256) void k_attn(
    const bf16_t* __restrict__ Qh, const bf16_t* __restrict__ Ql,
    const bf16_t* __restrict__ Kh, const bf16_t* __restrict__ Kl,
    const bf16_t* __restrict__ VT, bf16_t* __restrict__ Ob) {
  const int tid = threadIdx.x;
  const int wid = tid >> 6, lane = tid & 63;
  const int lo = lane & 15, hi = lane >> 4;
  const int bh = blockIdx.y, b = bh >> 4, h = bh & 15;
  const int q0 = (blockIdx.x * 4 + wid) * 16;
  const size_t base = (size_t)b * kSeq * kDModel + (size_t)h * kDk;
  const size_t qoff = base + (size_t)(q0 + lo) * kDModel + 8 * hi;

  bf16x8 qhf[4], qlf[4];
#pragma unroll
  for (int ks = 0; ks < 4; ++ks) {
    qhf[ks] = *(const bf16x8*)(Qh + qoff + ks * 32);
    qlf[ks] = *(const bf16x8*)(Ql + qoff + ks * 32);
  }
  f32x4 of[8];
  const f32x4 z = {0.f, 0.f, 0.f, 0.f};
#pragma unroll
  for (int di = 0; di < 8; ++di) of[di] = z;
  float m = -1e30f, l = 0.f;
  const bf16_t* Vb = VT + (size_t)bh * kDk * kSeq;
  const int nkt = (q0 >> 4) + 1;

  for (int t = 0; t < nkt; ++t) {
    const int key0 = t * 16;
    const size_t koff = base + (size_t)(key0 + lo) * kDModel + 8 * hi;
    f32x4 st = z;
#pragma unroll
    for (int ks = 0; ks < 4; ++ks) {
      const bf16x8 kh8 = *(const bf16x8*)(Kh + koff + ks * 32);
      const bf16x8 kl8 = *(const bf16x8*)(Kl + koff + ks * 32);
      st = mfma32(kh8, qhf[ks], st);  // kh*qh
      st = mfma32(kh8, qlf[ks], st);  // kh*ql
      st = mfma32(kl8, qhf[ks], st);  // kl*qh
    }
    float sv[4];
    float mt = -1e30f;
#pragma unroll
    for (int r = 0; r < 4; ++r) {
      float s = st[r];  // scale already folded into Q
      if (key0 + 4 * hi + r > q0 + lo) s = -1e30f;  // causal mask
      sv[r] = s;
      mt = fmaxf(mt, s);
    }
    mt = fmaxf(mt, __shfl_xor(mt, 16));
    mt = fmaxf(mt, __shfl_xor(mt, 32));
    const float mnew = fmaxf(m, mt);
    const float corr = __expf(m - mnew);
    float rs = 0.f;
    bf16x4 pb;
#pragma unroll
    for (int r = 0; r < 4; ++r) {
      const float pp = __expf(sv[r] - mnew);
      rs += pp;
      pb[r] = (bf16_t)pp;
    }
    rs += __shfl_xor(rs, 16);
    rs += __shfl_xor(rs, 32);
    l = l * corr + rs;
    m = mnew;
#pragma unroll
    for (int di = 0; di < 8; ++di) of[di] = of[di] * corr;
#pragma unroll
    for (int di = 0; di < 8; ++di) {
      const bf16x4 vf =
          *(const bf16x4*)(Vb + (size_t)(di * 16 + lo) * kSeq + key0 + 4 * hi);
      of[di] = mfma16(vf, pb, of[di]);
    }
  }

  const float linv = 1.f / l;
  const size_t obase = base + (size_t)(q0 + lo) * kDModel;
#pragma unroll
  for (int di = 0; di < 8; ++di) {
    bf16x4 ov;
#pragma unroll
    for (int r = 0; r < 4; ++r) ov[r] = (bf16_t)(of[di][r] * linv);
    *(bf16x4*)(Ob + obase + di * 16 + hi * 4) = ov;
  }
}

}  // namespace

extern "C" void kernel_launch(void* const* d_in, const int* in_sizes, int n_in,
                              void* d_out, int out_size, void* d_ws, size_t ws_size,
                              hipStream_t stream) {
  (void)in_sizes; (void)n_in; (void)out_size;
  const float* x = (const float*)d_in[0];
  const int* tokpos = (const int*)d_in[1];
  const float* wq = (const float*)d_in[2];
  const float* wk = (const float*)d_in[3];
  const float* wv = (const float*)d_in[4];
  const float* wo = (const float*)d_in[5];
  float* out = (float*)d_out;

  char* p = (char*)d_ws;
  auto take = [&](size_t bytes) { char* q = p; p += bytes; return q; };
  float* cost = (float*)take((size_t)kSeq * 64 * sizeof(float));
  float* sint = (float*)take((size_t)kSeq * 64 * sizeof(float));
  const size_t mat = (size_t)kM * kDModel * sizeof(bf16_t);        // 16.8 MB
  const size_t wmat = (size_t)kDModel * kDModel * sizeof(bf16_t);  // 8.4 MB
  bf16_t* xh = (bf16_t*)take(mat);
  bf16_t* xl = (bf16_t*)take(mat);
  bf16_t* wqth = (bf16_t*)take(wmat);
  bf16_t* wqtl = (bf16_t*)take(wmat);
  bf16_t* wkth = (bf16_t*)take(wmat);
  bf16_t* wktl = (bf16_t*)take(wmat);
  bf16_t* wvt = (bf16_t*)take(wmat);
  bf16_t* wot = (bf16_t*)take(wmat);
  bf16_t* qh = (bf16_t*)take(mat);
  bf16_t* ql = (bf16_t*)take(mat);
  bf16_t* kh = (bf16_t*)take(mat);
  bf16_t* kl = (bf16_t*)take(mat);
  bf16_t* vt = (bf16_t*)take(mat);
  bf16_t* ob = (bf16_t*)take(mat);
  if ((size_t)(p - (char*)d_ws) > ws_size) {
    fprintf(stderr, "MHA: workspace too small: need %zu have %zu\n",
            (size_t)(p - (char*)d_ws), ws_size);
    return;
  }

  k_rope_table<<<dim3(kSeq), dim3(64), 0, stream>>>(cost, sint);
  k_split_x<<<dim3((kM * kDModel) / (256 * 4)), dim3(256), 0, stream>>>(
      x, xh, xl, kM * kDModel);
  {
    dim3 tb(32, 8), tg(kDModel / 32, kDModel / 32);
    k_transpose_w<<<tg, tb, 0, stream>>>(wq, wqth, wqtl);
    k_transpose_w<<<tg, tb, 0, stream>>>(wk, wkth, wktl);
    k_transpose_w<<<tg, tb, 0, stream>>>(wv, wvt, nullptr);
    k_transpose_w<<<tg, tb, 0, stream>>>(wo, wot, nullptr);
  }
  const dim3 gg(kDModel / 128, kM / 128);
  k_gemm<3, 1><<<gg, 256, 0, stream>>>(xh, xl, wqth, wqtl, qh, ql, tokpos, cost,
                                       sint, kQScale, kM, kDModel, kDModel);
  k_gemm<3, 1><<<gg, 256, 0, stream>>>(xh, xl, wkth, wktl, kh, kl, tokpos, cost,
                                       sint, 1.0f, kM, kDModel, kDModel);
  k_gemm<1, 2><<<gg, 256, 0, stream>>>(xh, nullptr, wvt, nullptr, vt, nullptr,
                                       nullptr, nullptr, nullptr, 1.0f, kM,
                                       kDModel, kDModel);
  k_attn<<<dim3(kSeq / 64, kBatch * kHeads), dim3(256), 0, stream>>>(qh, ql, kh,
                                                                     kl, vt, ob);
  k_gemm<1, 0><<<gg, 256, 0, stream>>>(ob, nullptr, wot, nullptr, out, nullptr,
                                       nullptr, nullptr, nullptr, 1.0f, kM,
                                       kDModel, kDModel);
}

// Round 2
// 572.356 us; speedup vs baseline: 2.1588x; 2.1588x over previous
//
#include <hip/hip_runtime.h>
#include <hip/hip_bf16.h>
#include <cstdio>

namespace {

constexpr int kSeq = 2048;
constexpr int kDModel = 2048;
constexpr int kHeads = 16;
constexpr int kDk = 128;
constexpr int kBatch = 2;
constexpr int kM = kBatch * kSeq;  // 4096 rows of x
constexpr float kQScale = 0.08838834764831845f;  // 1/sqrt(128)

typedef __bf16 bf16_t;
typedef __bf16 bf16x8 __attribute__((ext_vector_type(8)));
typedef __bf16 bf16x4 __attribute__((ext_vector_type(4)));
typedef float f32x4 __attribute__((ext_vector_type(4)));
typedef short s16x4 __attribute__((ext_vector_type(4)));

__device__ __forceinline__ f32x4 mfma32(bf16x8 a, bf16x8 b, f32x4 c) {
  return __builtin_amdgcn_mfma_f32_16x16x32_bf16(a, b, c, 0, 0, 0);
}

#if __has_builtin(__builtin_amdgcn_mfma_f32_16x16x16_bf16)
__device__ __forceinline__ f32x4 mfma16(bf16x4 a, bf16x4 b, f32x4 c) {
  return __builtin_amdgcn_mfma_f32_16x16x16_bf16(a, b, c, 0, 0, 0);
}
#else
__device__ __forceinline__ f32x4 mfma16(bf16x4 a, bf16x4 b, f32x4 c) {
  union U { bf16x4 b; s16x4 s; } ua, ub;
  ua.b = a; ub.b = b;
  return __builtin_amdgcn_mfma_f32_16x16x16bf16_1k(ua.s, ub.s, c, 0, 0, 0);
}
#endif

using gas_void = const __attribute__((address_space(1))) void;
using las_void = __attribute__((address_space(3))) void;

__device__ __forceinline__ void gload_lds16(const bf16_t* g, bf16_t* l) {
  __builtin_amdgcn_global_load_lds((gas_void*)g, (las_void*)l, 16, 0, 0);
}

// ---------------- RoPE table (fp64 for max fidelity vs np reference) --------
__global__ void k_rope_table(float* __restrict__ cost, float* __restrict__ sint) {
  const int p = blockIdx.x;
  const int i = threadIdx.x;
  const double inv = exp(-(double)(2 * i) * 9.210340371976184 / 128.0);
  const double ang = (double)p * inv;
  cost[p * 64 + i] = (float)cos(ang);
  sint[p * 64 + i] = (float)sin(ang);
}

// ---------------- x -> (hi,lo) bf16 split -----------------------------------
__global__ void k_split_x(const float* __restrict__ x, bf16_t* __restrict__ xh,
                          bf16_t* __restrict__ xl, int n) {
  const int idx = (blockIdx.x * blockDim.x + threadIdx.x) * 4;
  if (idx >= n) return;
  const float4 v = *(const float4*)(x + idx);
  const float vv[4] = {v.x, v.y, v.z, v.w};
  bf16x4 hv, lv;
#pragma unroll
  for (int j = 0; j < 4; ++j) {
    const bf16_t h = (bf16_t)vv[j];
    hv[j] = h;
    lv[j] = (bf16_t)(vv[j] - (float)h);
  }
  *(bf16x4*)(xh + idx) = hv;
  *(bf16x4*)(xl + idx) = lv;
}

// ---------------- W (fp32 [K][N]) -> W^T bf16 hi(/lo) [N][K] ----------------
__global__ void k_transpose_w(const float* __restrict__ w, bf16_t* __restrict__ wth,
                              bf16_t* __restrict__ wtl) {
  __shared__ float tile[32][33];
  const int bx = blockIdx.x * 32;  // n
  const int by = blockIdx.y * 32;  // k
  const int tx = threadIdx.x, ty = threadIdx.y;
#pragma unroll
  for (int i = 0; i < 32; i += 8)
    tile[ty + i][tx] = w[(size_t)(by + ty + i) * kDModel + bx + tx];
  __syncthreads();
#pragma unroll
  for (int i = 0; i < 32; i += 8) {
    const float v = tile[tx][ty + i];
    const size_t o = (size_t)(bx + ty + i) * kDModel + by + tx;
    const bf16_t h = (bf16_t)v;
    wth[o] = h;
    if (wtl) wtl[o] = (bf16_t)(v - (float)h);
  }
}

// ---------------- Tiled MFMA GEMM: C = A @ B (B given transposed [N][K]) ----
// TERMS==3: C = Ah*Bh + Ah*Bl + Al*Bh (split-bf16 ~fp32 accuracy)
// EPI: 0 = store fp32 row-major; 1 = RoPE + split-bf16 store (Q/K);
//      2 = store bf16 V^T per head [bh*128+d][s]
template <int TERMS, int EPI>
__global__ __launch_bounds__(256) void k_gemm(
    const bf16_t* __restrict__ Ah, const bf16_t* __restrict__ Al,
    const bf16_t* __restrict__ Bh, const bf16_t* __restrict__ Bl,
    void* __restrict__ O0, void* __restrict__ O1,
    const int* __restrict__ tokpos, const float* __restrict__ cost,
    const float* __restrict__ sint, float scale, int M, int N, int K) {
  __shared__ __align__(16) bf16_t sAh[128 * 32];
  __shared__ __align__(16) bf16_t sBh[128 * 32];
  __shared__ __align__(16) bf16_t sAl[TERMS == 3 ? 128 * 32 : 8];
  __shared__ __align__(16) bf16_t sBl[TERMS == 3 ? 128 * 32 : 8];

  const int tid = threadIdx.x;
  const int wid = tid >> 6;
  const int lane = tid & 63;
  const int lo = lane & 15, hi = lane >> 4;
  const int wr = wid >> 1, wc = wid & 1;
  const int m0 = blockIdx.y * 128, n0 = blockIdx.x * 128;

  f32x4 acc[4][4];
  const f32x4 z = {0.f, 0.f, 0.f, 0.f};
#pragma unroll
  for (int i = 0; i < 4; ++i)
#pragma unroll
    for (int j = 0; j < 4; ++j) acc[i][j] = z;

  const int rr = wid * 16 + (lane >> 2);  // staging row (chunk 0)
  const int kk = (lane & 3) * 8;          // staging k offset

  for (int k0 = 0; k0 < K; k0 += 32) {
    __syncthreads();
    {
      const bf16_t* gA = Ah + (size_t)(m0 + rr) * K + k0 + kk;
      gload_lds16(gA, sAh + wid * 512);
      gload_lds16(gA + (size_t)64 * K, sAh + 2048 + wid * 512);
      const bf16_t* gB = Bh + (size_t)(n0 + rr) * K + k0 + kk;
      gload_lds16(gB, sBh + wid * 512);
      gload_lds16(gB + (size_t)64 * K, sBh + 2048 + wid * 512);
      if constexpr (TERMS == 3) {
        const bf16_t* gAl = Al + (size_t)(m0 + rr) * K + k0 + kk;
        gload_lds16(gAl, sAl + wid * 512);
        gload_lds16(gAl + (size_t)64 * K, sAl + 2048 + wid * 512);
        const bf16_t* gBl = Bl + (size_t)(n0 + rr) * K + k0 + kk;
        gload_lds16(gBl, sBl + wid * 512);
        gload_lds16(gBl + (size_t)64 * K, sBl + 2048 + wid * 512);
      }
    }
    __syncthreads();
    bf16x8 fah[4], fbh[4];
#pragma unroll
    for (int mi = 0; mi < 4; ++mi)
      fah[mi] = *(const bf16x8*)(sAh + (wr * 64 + mi * 16 + lo) * 32 + 8 * hi);
#pragma unroll
    for (int ni = 0; ni < 4; ++ni)
      fbh[ni] = *(const bf16x8*)(sBh + (wc * 64 + ni * 16 + lo) * 32 + 8 * hi);
    if constexpr (TERMS == 3) {
      bf16x8 fal[4], fbl[4];
#pragma unroll
      for (int mi = 0; mi < 4; ++mi)
        fal[mi] = *(const bf16x8*)(sAl + (wr * 64 + mi * 16 + lo) * 32 + 8 * hi);
#pragma unroll
      for (int ni = 0; ni < 4; ++ni)
        fbl[ni] = *(const bf16x8*)(sBl + (wc * 64 + ni * 16 + lo) * 32 + 8 * hi);
#pragma unroll
      for (int mi = 0; mi < 4; ++mi)
#pragma unroll
        for (int ni = 0; ni < 4; ++ni) {
          acc[mi][ni] = mfma32(fah[mi], fbh[ni], acc[mi][ni]);
          acc[mi][ni] = mfma32(fah[mi], fbl[ni], acc[mi][ni]);
          acc[mi][ni] = mfma32(fal[mi], fbh[ni], acc[mi][ni]);
        }
    } else {
#pragma unroll
      for (int mi = 0; mi < 4; ++mi)
#pragma unroll
        for (int ni = 0; ni < 4; ++ni)
          acc[mi][ni] = mfma32(fah[mi], fbh[ni], acc[mi][ni]);
    }
  }

  if constexpr (EPI == 0) {
    float* C = (float*)O0;
#pragma unroll
    for (int mi = 0; mi < 4; ++mi)
#pragma unroll
      for (int ni = 0; ni < 4; ++ni)
#pragma unroll
        for (int r = 0; r < 4; ++r) {
          const int row = m0 + wr * 64 + mi * 16 + hi * 4 + r;
          const int col = n0 + wc * 64 + ni * 16 + lo;
          C[(size_t)row * N + col] = acc[mi][ni][r];
        }
  } else if constexpr (EPI == 1) {
    bf16_t* Xh = (bf16_t*)O0;
    bf16_t* Xl = (bf16_t*)O1;
    const int is64 = (tokpos[1] == 0) ? 1 : 0;  // int64 positions -> high word 0
#pragma unroll
    for (int mi = 0; mi < 4; ++mi) {
#pragma unroll
      for (int r = 0; r < 4; ++r) {
        const int row = m0 + wr * 64 + mi * 16 + hi * 4 + r;
        const int pos = is64 ? tokpos[2 * row] : tokpos[row];
#pragma unroll
        for (int ni = 0; ni < 4; ++ni) {
          const int col = n0 + wc * 64 + ni * 16 + lo;
          const float v = acc[mi][ni][r] * scale;
          const float pv = __shfl_xor(v, 1);  // paired column (col^1)
          const int ip = (col & 127) >> 1;
          const float c = cost[pos * 64 + ip];
          const float sn = sint[pos * 64 + ip];
          const float sgn = (lo & 1) ? sn : -sn;  // even: -x_o*s ; odd: +x_e*s
          const float rv = v * c + pv * sgn;
          const bf16_t hb = (bf16_t)rv;
          const size_t o = (size_t)row * N + col;
          Xh[o] = hb;
          Xl[o] = (bf16_t)(rv - (float)hb);
        }
      }
    }
  } else {  // EPI == 2 : V^T
    bf16_t* VT = (bf16_t*)O0;
#pragma unroll
    for (int mi = 0; mi < 4; ++mi)
#pragma unroll
      for (int ni = 0; ni < 4; ++ni) {
        const int col = n0 + wc * 64 + ni * 16 + lo;
        const int h = col >> 7, d = col & 127;
        const int rowb = m0 + wr * 64 + mi * 16 + hi * 4;
        const int b = rowb >> 11, s = rowb & (kSeq - 1);
        bf16x4 ov;
#pragma unroll
        for (int r = 0; r < 4; ++r) ov[r] = (bf16_t)acc[mi][ni][r];
        *(bf16x4*)(VT + ((size_t)((b * kHeads + h) * kDk + d)) * kSeq + s) = ov;
      }
  }
}

// ---------------- Causal flash attention, LDS-staged ------------------------
// Block: 4 waves x 32 q-rows = 128 q. KV tile = 64 keys staged in LDS:
//   sKh/sKl [64 rows][128 k] bf16, XOR-swizzled 16B chunks (chunk ^ (row&7))
//   sVT     [128 d ][64 s ] bf16, XOR-swizzled 16B chunks (chunk ^ (d&7))
// Staged via global_load_lds with pre-swizzled global source (rule #21).
// QK^T swapped: st = mfma32(A=K, B=Q) -> col=q=lane&15 (softmax stats per
// lane column, reduce via shfl_xor 16/32). PV: of = mfma16(A=V^T, B=P^T),
// st's C-fragment layout == mfma16 B-operand layout (k = hi*4+r).
__global__ __launch_bounds__(256) void k_attn2(
    const bf16_t* __restrict__ Qh, const bf16_t* __restrict__ Ql,
    const bf16_t* __restrict__ Kh, const bf16_t* __restrict__ Kl,
    const bf16_t* __restrict__ VT, bf16_t* __restrict__ Ob) {
  __shared__ __align__(16) bf16_t sKh[64 * 128];
  __shared__ __align__(16) bf16_t sKl[64 * 128];
  __shared__ __align__(16) bf16_t sVT[128 * 64];

  const int tid = threadIdx.x;
  const int wid = tid >> 6, lane = tid & 63;
  const int lo = lane & 15, hi = lane >> 4;
  const int bh = blockIdx.y, b = bh >> 4, h = bh & 15;
  const int qi = gridDim.x - 1 - blockIdx.x;  // big blocks dispatch first
  const int q0 = qi * 128;
  const int qw = q0 + wid * 32;  // this wave's 32 q-rows

  // ---- Q fragments (persistent) ----
  bf16x8 qhf[4][2], qlf[4][2];
  {
    const size_t qbase =
        (size_t)(b * kSeq + qw + lo) * kDModel + h * kDk + hi * 8;
#pragma unroll
    for (int qt = 0; qt < 2; ++qt)
#pragma unroll
      for (int ks = 0; ks < 4; ++ks) {
        const size_t o = qbase + (size_t)qt * 16 * kDModel + ks * 32;
        qhf[ks][qt] = *(const bf16x8*)(Qh + o);
        qlf[ks][qt] = *(const bf16x8*)(Ql + o);
      }
  }

  f32x4 of[8][2];
  const f32x4 z = {0.f, 0.f, 0.f, 0.f};
#pragma unroll
  for (int di = 0; di < 8; ++di) {
    of[di][0] = z;
    of[di][1] = z;
  }
  float m[2] = {-3e38f, -3e38f};
  float l[2] = {0.f, 0.f};

  const int nkv = q0 / 64 + 2;  // tiles; last 2 need the causal mask

  for (int t = 0; t < nkv; ++t) {
    const int kv0 = t * 64;
    __syncthreads();  // previous tile's compute done before overwrite
    // ---- stage K (hi+lo) rows kv0..kv0+63, swizzled source ----
#pragma unroll
    for (int i = 0; i < 4; ++i) {
      const int r = wid * 16 + i * 4 + (lane >> 4);
      const int g = (lane & 15) ^ (r & 7);
      const size_t src = (size_t)(b * kSeq + kv0 + r) * kDModel + h * kDk + g * 8;
      gload_lds16(Kh + src, sKh + (wid * 16 + i * 4) * 128);
      gload_lds16(Kl + src, sKl + (wid * 16 + i * 4) * 128);
    }
    // ---- stage V^T rows (d) 0..127, keys kv0..kv0+63, swizzled ----
#pragma unroll
    for (int i = 0; i < 4; ++i) {
      const int d = wid * 32 + i * 8 + (lane >> 3);
      const int g = (lane & 7) ^ (d & 7);
      const size_t src = (size_t)(bh * kDk + d) * kSeq + kv0 + g * 8;
      gload_lds16(VT + src, sVT + (wid * 32 + i * 8) * 64);
    }
    __syncthreads();  // staging visible (barrier drains vmcnt)

    const bool masked = (t >= nkv - 2);

    // ---- QK^T (3-term split) ----
    f32x4 st[4][2];
#pragma unroll
    for (int kt = 0; kt < 4; ++kt) {
      st[kt][0] = z;
      st[kt][1] = z;
    }
#pragma unroll
    for (int kt = 0; kt < 4; ++kt) {
#pragma unroll
      for (int ks = 0; ks < 4; ++ks) {
        const int krow = kt * 16 + lo;
        const int ka = krow * 128 + (((ks * 4 + hi) ^ (krow & 7)) * 8);
        const bf16x8 kh8 = *(const bf16x8*)(sKh + ka);
        const bf16x8 kl8 = *(const bf16x8*)(sKl + ka);
#pragma unroll
        for (int qt = 0; qt < 2; ++qt) {
          st[kt][qt] = mfma32(kh8, qhf[ks][qt], st[kt][qt]);
          st[kt][qt] = mfma32(kh8, qlf[ks][qt], st[kt][qt]);
          st[kt][qt] = mfma32(kl8, qhf[ks][qt], st[kt][qt]);
        }
      }
    }

    // ---- online softmax per q column (q = lane&15 within qt tile) ----
    bf16x4 pb[4][2];
#pragma unroll
    for (int qt = 0; qt < 2; ++qt) {
      const int q = qw + qt * 16 + lo;
      float mt = -3e38f;
#pragma unroll
      for (int kt = 0; kt < 4; ++kt)
#pragma unroll
        for (int r = 0; r < 4; ++r) {
          float s = st[kt][qt][r];
          if (masked && (kv0 + kt * 16 + hi * 4 + r > q)) s = -1e30f;
          st[kt][qt][r] = s;
          mt = fmaxf(mt, s);
        }
      mt = fmaxf(mt, __shfl_xor(mt, 16));
      mt = fmaxf(mt, __shfl_xor(mt, 32));
      const float mnew = fmaxf(m[qt], mt);
      const float corr = __expf(m[qt] - mnew);
      float rs = 0.f;
#pragma unroll
      for (int kt = 0; kt < 4; ++kt) {
        bf16x4 pv;
#pragma unroll
        for (int r = 0; r < 4; ++r) {
          const float pp = __expf(st[kt][qt][r] - mnew);
          rs += pp;
          pv[r] = (bf16_t)pp;
        }
        pb[kt][qt] = pv;
      }
      rs += __shfl_xor(rs, 16);
      rs += __shfl_xor(rs, 32);
      l[qt] = l[qt] * corr + rs;
      m[qt] = mnew;
#pragma unroll
      for (int di = 0; di < 8; ++di) of[di][qt] = of[di][qt] * corr;
    }

    // ---- PV: of[d][q] += V^T * P^T ----
#pragma unroll
    for (int di = 0; di < 8; ++di) {
      const int d = di * 16 + lo;
#pragma unroll
      for (int kt = 0; kt < 4; ++kt) {
        const int va =
            d * 64 + (((kt * 2 + (hi >> 1)) ^ (d & 7)) * 8) + (hi & 1) * 4;
        const bf16x4 vf = *(const bf16x4*)(sVT + va);
        of[di][0] = mfma16(vf, pb[kt][0], of[di][0]);
        of[di][1] = mfma16(vf, pb[kt][1], of[di][1]);
      }
    }
  }

  // ---- epilogue: O^T fragments -> Ob[b][q][h*128+d] ----
#pragma unroll
  for (int qt = 0; qt < 2; ++qt) {
    const float linv = 1.f / l[qt];
    const size_t ob =
        (size_t)(b * kSeq + qw + qt * 16 + lo) * kDModel + h * kDk + hi * 4;
#pragma unroll
    for (int di = 0; di < 8; ++di) {
      bf16x4 ov;
#pragma unroll
      for (int r = 0; r < 4; ++r) ov[r] = (bf16_t)(of[di][qt][r] * linv);
      *(bf16x4*)(Ob + ob + di * 16) = ov;
    }
  }
}

}  // namespace

extern "C" void kernel_launch(void* const* d_in, const int* in_sizes, int n_in,
                              void* d_out, int out_size, void* d_ws, size_t ws_size,
                              hipStream_t stream) {
  (void)in_sizes; (void)n_in; (void)out_size;
  const float* x = (const float*)d_in[0];
  const int* tokpos = (const int*)d_in[1];
  const float* wq = (const float*)d_in[2];
  const float* wk = (const float*)d_in[3];
  const float* wv = (const float*)d_in[4];
  const float* wo = (const float*)d_in[5];
  float* out = (float*)d_out;

  char* p = (char*)d_ws;
  auto take = [&](size_t bytes) { char* q = p; p += bytes; return q; };
  float* cost = (float*)take((size_t)kSeq * 64 * sizeof(float));
  float* sint = (float*)take((size_t)kSeq * 64 * sizeof(float));
  const size_t mat = (size_t)kM * kDModel * sizeof(bf16_t);        // 16.8 MB
  const size_t wmat = (size_t)kDModel * kDModel * sizeof(bf16_t);  // 8.4 MB
  bf16_t* xh = (bf16_t*)take(mat);
  bf16_t* xl = (bf16_t*)take(mat);
  bf16_t* wqth = (bf16_t*)take(wmat);
  bf16_t* wqtl = (bf16_t*)take(wmat);
  bf16_t* wkth = (bf16_t*)take(wmat);
  bf16_t* wktl = (bf16_t*)take(wmat);
  bf16_t* wvt = (bf16_t*)take(wmat);
  bf16_t* wot = (bf16_t*)take(wmat);
  bf16_t* qh = (bf16_t*)take(mat);
  bf16_t* ql = (bf16_t*)take(mat);
  bf16_t* kh = (bf16_t*)take(mat);
  bf16_t* kl = (bf16_t*)take(mat);
  bf16_t* vt = (bf16_t*)take(mat);
  bf16_t* ob = (bf16_t*)take(mat);
  if ((size_t)(p - (char*)d_ws) > ws_size) {
    fprintf(stderr, "MHA: workspace too small: need %zu have %zu\n",
            (size_t)(p - (char*)d_ws), ws_size);
    return;
  }

  k_rope_table<<<dim3(kSeq), dim3(64), 0, stream>>>(cost, sint);
  k_split_x<<<dim3((kM * kDModel) / (256 * 4)), dim3(256), 0, stream>>>(
      x, xh, xl, kM * kDModel);
  {
    dim3 tb(32, 8), tg(kDModel / 32, kDModel / 32);
    k_transpose_w<<<tg, tb, 0, stream>>>(wq, wqth, wqtl);
    k_transpose_w<<<tg, tb, 0, stream>>>(wk, wkth, wktl);
    k_transpose_w<<<tg, tb, 0, stream>>>(wv, wvt, nullptr);
    k_transpose_w<<<tg, tb, 0, stream>>>(wo, wot, nullptr);
  }
  const dim3 gg(kDModel / 128, kM / 128);
  k_gemm<3, 1><<<gg, 256, 0, stream>>>(xh, xl, wqth, wqtl, qh, ql, tokpos, cost,
                                       sint, kQScale, kM, kDModel, kDModel);
  k_gemm<3, 1><<<gg, 256, 0, stream>>>(xh, xl, wkth, wktl, kh, kl, tokpos, cost,
                                       sint, 1.0f, kM, kDModel, kDModel);
  k_gemm<1, 2><<<gg, 256, 0, stream>>>(xh, nullptr, wvt, nullptr, vt, nullptr,
                                       nullptr, nullptr, nullptr, 1.0f, kM,
                                       kDModel, kDModel);
  k_attn2<<<dim3(kSeq / 128, kBatch * kHeads), dim3(256), 0, stream>>>(
      qh, ql, kh, kl, vt, ob);
  k_gemm<1, 0><<<gg, 256, 0, stream>>>(ob, nullptr, wot, nullptr, out, nullptr,
                                       nullptr, nullptr, nullptr, 1.0f, kM,
                                       kDModel, kDModel);
}

// Round 3
// 511.549 us; speedup vs baseline: 2.4154x; 1.1189x over previous
//
#include <hip/hip_runtime.h>
#include <hip/hip_bf16.h>
#include <cstdio>

namespace {

constexpr int kSeq = 2048;
constexpr int kDModel = 2048;
constexpr int kHeads = 16;
constexpr int kDk = 128;
constexpr int kBatch = 2;
constexpr int kM = kBatch * kSeq;  // 4096 rows of x
constexpr float kQScale = 0.08838834764831845f;  // 1/sqrt(128)

typedef __bf16 bf16_t;
typedef __bf16 bf16x8 __attribute__((ext_vector_type(8)));
typedef __bf16 bf16x4 __attribute__((ext_vector_type(4)));
typedef float f32x4 __attribute__((ext_vector_type(4)));
typedef short s16x4 __attribute__((ext_vector_type(4)));

__device__ __forceinline__ f32x4 mfma32(bf16x8 a, bf16x8 b, f32x4 c) {
  return __builtin_amdgcn_mfma_f32_16x16x32_bf16(a, b, c, 0, 0, 0);
}

#if __has_builtin(__builtin_amdgcn_mfma_f32_16x16x16_bf16)
__device__ __forceinline__ f32x4 mfma16(bf16x4 a, bf16x4 b, f32x4 c) {
  return __builtin_amdgcn_mfma_f32_16x16x16_bf16(a, b, c, 0, 0, 0);
}
#else
__device__ __forceinline__ f32x4 mfma16(bf16x4 a, bf16x4 b, f32x4 c) {
  union U { bf16x4 b; s16x4 s; } ua, ub;
  ua.b = a; ub.b = b;
  return __builtin_amdgcn_mfma_f32_16x16x16bf16_1k(ua.s, ub.s, c, 0, 0, 0);
}
#endif

using gas_void = const __attribute__((address_space(1))) void;
using las_void = __attribute__((address_space(3))) void;

__device__ __forceinline__ void gload_lds16(const bf16_t* g, bf16_t* l) {
  __builtin_amdgcn_global_load_lds((gas_void*)g, (las_void*)l, 16, 0, 0);
}

// ---------------- RoPE table (fp64 for max fidelity vs np reference) --------
__global__ void k_rope_table(float* __restrict__ cost, float* __restrict__ sint) {
  const int p = blockIdx.x;
  const int i = threadIdx.x;
  const double inv = exp(-(double)(2 * i) * 9.210340371976184 / 128.0);
  const double ang = (double)p * inv;
  cost[p * 64 + i] = (float)cos(ang);
  sint[p * 64 + i] = (float)sin(ang);
}

// ---------------- x -> (hi,lo) bf16 split -----------------------------------
__global__ void k_split_x(const float* __restrict__ x, bf16_t* __restrict__ xh,
                          bf16_t* __restrict__ xl, int n) {
  const int idx = (blockIdx.x * blockDim.x + threadIdx.x) * 4;
  if (idx >= n) return;
  const float4 v = *(const float4*)(x + idx);
  const float vv[4] = {v.x, v.y, v.z, v.w};
  bf16x4 hv, lv;
#pragma unroll
  for (int j = 0; j < 4; ++j) {
    const bf16_t h = (bf16_t)vv[j];
    hv[j] = h;
    lv[j] = (bf16_t)(vv[j] - (float)h);
  }
  *(bf16x4*)(xh + idx) = hv;
  *(bf16x4*)(xl + idx) = lv;
}

// ---------------- W (fp32 [K][N]) -> W^T bf16 hi(/lo) [N][K] ----------------
__global__ void k_transpose_w(const float* __restrict__ w, bf16_t* __restrict__ wth,
                              bf16_t* __restrict__ wtl) {
  __shared__ float tile[32][33];
  const int bx = blockIdx.x * 32;  // n
  const int by = blockIdx.y * 32;  // k
  const int tx = threadIdx.x, ty = threadIdx.y;
#pragma unroll
  for (int i = 0; i < 32; i += 8)
    tile[ty + i][tx] = w[(size_t)(by + ty + i) * kDModel + bx + tx];
  __syncthreads();
#pragma unroll
  for (int i = 0; i < 32; i += 8) {
    const float v = tile[tx][ty + i];
    const size_t o = (size_t)(bx + ty + i) * kDModel + by + tx;
    const bf16_t h = (bf16_t)v;
    wth[o] = h;
    if (wtl) wtl[o] = (bf16_t)(v - (float)h);
  }
}

// ---------------- Tiled MFMA GEMM: C = A @ B (B given transposed [N][K]) ----
// TERMS==3: C = Ah*Bh + Ah*Bl + Al*Bh (split-bf16 ~fp32 accuracy)
// EPI: 0 = store fp32 row-major; 1 = RoPE + split-bf16 store (Q/K);
//      2 = store bf16 V^T per head [bh*128+d][s]
template <int TERMS, int EPI>
__global__ __launch_bounds__(256) void k_gemm(
    const bf16_t* __restrict__ Ah, const bf16_t* __restrict__ Al,
    const bf16_t* __restrict__ Bh, const bf16_t* __restrict__ Bl,
    void* __restrict__ O0, void* __restrict__ O1,
    const int* __restrict__ tokpos, const float* __restrict__ cost,
    const float* __restrict__ sint, float scale, int M, int N, int K) {
  __shared__ __align__(16) bf16_t sAh[128 * 32];
  __shared__ __align__(16) bf16_t sBh[128 * 32];
  __shared__ __align__(16) bf16_t sAl[TERMS == 3 ? 128 * 32 : 8];
  __shared__ __align__(16) bf16_t sBl[TERMS == 3 ? 128 * 32 : 8];

  const int tid = threadIdx.x;
  const int wid = tid >> 6;
  const int lane = tid & 63;
  const int lo = lane & 15, hi = lane >> 4;
  const int wr = wid >> 1, wc = wid & 1;
  // m204-bijective XCD swizzle (total blocks divisible by 8)
  const int flat = blockIdx.x + blockIdx.y * gridDim.x;
  const int wgid = (flat & 7) * ((gridDim.x * gridDim.y) >> 3) + (flat >> 3);
  const int m0 = (wgid / gridDim.x) * 128, n0 = (wgid % gridDim.x) * 128;

  f32x4 acc[4][4];
  const f32x4 z = {0.f, 0.f, 0.f, 0.f};
#pragma unroll
  for (int i = 0; i < 4; ++i)
#pragma unroll
    for (int j = 0; j < 4; ++j) acc[i][j] = z;

  const int rr = wid * 16 + (lane >> 2);  // staging row (chunk 0)
  const int kk = (lane & 3) * 8;          // staging k offset

  for (int k0 = 0; k0 < K; k0 += 32) {
    __syncthreads();
    {
      const bf16_t* gA = Ah + (size_t)(m0 + rr) * K + k0 + kk;
      gload_lds16(gA, sAh + wid * 512);
      gload_lds16(gA + (size_t)64 * K, sAh + 2048 + wid * 512);
      const bf16_t* gB = Bh + (size_t)(n0 + rr) * K + k0 + kk;
      gload_lds16(gB, sBh + wid * 512);
      gload_lds16(gB + (size_t)64 * K, sBh + 2048 + wid * 512);
      if constexpr (TERMS == 3) {
        const bf16_t* gAl = Al + (size_t)(m0 + rr) * K + k0 + kk;
        gload_lds16(gAl, sAl + wid * 512);
        gload_lds16(gAl + (size_t)64 * K, sAl + 2048 + wid * 512);
        const bf16_t* gBl = Bl + (size_t)(n0 + rr) * K + k0 + kk;
        gload_lds16(gBl, sBl + wid * 512);
        gload_lds16(gBl + (size_t)64 * K, sBl + 2048 + wid * 512);
      }
    }
    __syncthreads();
    bf16x8 fah[4], fbh[4];
#pragma unroll
    for (int mi = 0; mi < 4; ++mi)
      fah[mi] = *(const bf16x8*)(sAh + (wr * 64 + mi * 16 + lo) * 32 + 8 * hi);
#pragma unroll
    for (int ni = 0; ni < 4; ++ni)
      fbh[ni] = *(const bf16x8*)(sBh + (wc * 64 + ni * 16 + lo) * 32 + 8 * hi);
    if constexpr (TERMS == 3) {
      bf16x8 fal[4], fbl[4];
#pragma unroll
      for (int mi = 0; mi < 4; ++mi)
        fal[mi] = *(const bf16x8*)(sAl + (wr * 64 + mi * 16 + lo) * 32 + 8 * hi);
#pragma unroll
      for (int ni = 0; ni < 4; ++ni)
        fbl[ni] = *(const bf16x8*)(sBl + (wc * 64 + ni * 16 + lo) * 32 + 8 * hi);
#pragma unroll
      for (int mi = 0; mi < 4; ++mi)
#pragma unroll
        for (int ni = 0; ni < 4; ++ni) {
          acc[mi][ni] = mfma32(fah[mi], fbh[ni], acc[mi][ni]);
          acc[mi][ni] = mfma32(fah[mi], fbl[ni], acc[mi][ni]);
          acc[mi][ni] = mfma32(fal[mi], fbh[ni], acc[mi][ni]);
        }
    } else {
#pragma unroll
      for (int mi = 0; mi < 4; ++mi)
#pragma unroll
        for (int ni = 0; ni < 4; ++ni)
          acc[mi][ni] = mfma32(fah[mi], fbh[ni], acc[mi][ni]);
    }
  }

  if constexpr (EPI == 0) {
    float* C = (float*)O0;
#pragma unroll
    for (int mi = 0; mi < 4; ++mi)
#pragma unroll
      for (int ni = 0; ni < 4; ++ni)
#pragma unroll
        for (int r = 0; r < 4; ++r) {
          const int row = m0 + wr * 64 + mi * 16 + hi * 4 + r;
          const int col = n0 + wc * 64 + ni * 16 + lo;
          C[(size_t)row * N + col] = acc[mi][ni][r];
        }
  } else if constexpr (EPI == 1) {
    bf16_t* Xh = (bf16_t*)O0;
    bf16_t* Xl = (bf16_t*)O1;
    const int is64 = (tokpos[1] == 0) ? 1 : 0;  // int64 positions -> high word 0
#pragma unroll
    for (int mi = 0; mi < 4; ++mi) {
#pragma unroll
      for (int r = 0; r < 4; ++r) {
        const int row = m0 + wr * 64 + mi * 16 + hi * 4 + r;
        const int pos = is64 ? tokpos[2 * row] : tokpos[row];
#pragma unroll
        for (int ni = 0; ni < 4; ++ni) {
          const int col = n0 + wc * 64 + ni * 16 + lo;
          const float v = acc[mi][ni][r] * scale;
          const float pv = __shfl_xor(v, 1);  // paired column (col^1)
          const int ip = (col & 127) >> 1;
          const float c = cost[pos * 64 + ip];
          const float sn = sint[pos * 64 + ip];
          const float sgn = (lo & 1) ? sn : -sn;  // even: -x_o*s ; odd: +x_e*s
          const float rv = v * c + pv * sgn;
          const bf16_t hb = (bf16_t)rv;
          const size_t o = (size_t)row * N + col;
          Xh[o] = hb;
          Xl[o] = (bf16_t)(rv - (float)hb);
        }
      }
    }
  } else {  // EPI == 2 : V^T
    bf16_t* VT = (bf16_t*)O0;
#pragma unroll
    for (int mi = 0; mi < 4; ++mi)
#pragma unroll
      for (int ni = 0; ni < 4; ++ni) {
        const int col = n0 + wc * 64 + ni * 16 + lo;
        const int h = col >> 7, d = col & 127;
        const int rowb = m0 + wr * 64 + mi * 16 + hi * 4;
        const int b = rowb >> 11, s = rowb & (kSeq - 1);
        bf16x4 ov;
#pragma unroll
        for (int r = 0; r < 4; ++r) ov[r] = (bf16_t)acc[mi][ni][r];
        *(bf16x4*)(VT + ((size_t)((b * kHeads + h) * kDk + d)) * kSeq + s) = ov;
      }
  }
}

// ---------------- Causal flash attention, double-buffered -------------------
// 4 waves x 32 q = QBLK 128. KV tile = 32 keys, 2-phase pipelined LDS:
//   sK[buf][h/l] [32 rows][128 k]  (16B chunks swizzled: chunk ^ (row&7))
//   sV[buf]      [128 d ][32 s ]  (16B chunks swizzled: chunk ^ ((d>>1)&3))
// Loop: STAGE(next buf) issued FIRST, then compute(cur), then one
// __syncthreads (drains vmcnt) per tile -> HBM/L2 latency hides under compute.
__global__ __launch_bounds__(256) void k_attn3(
    const bf16_t* __restrict__ Qh, const bf16_t* __restrict__ Ql,
    const bf16_t* __restrict__ Kh, const bf16_t* __restrict__ Kl,
    const bf16_t* __restrict__ VT, bf16_t* __restrict__ Ob) {
  __shared__ __align__(16) bf16_t sK[2][2][32 * 128];
  __shared__ __align__(16) bf16_t sV[2][128 * 32];

  const int tid = threadIdx.x;
  const int wid = tid >> 6, lane = tid & 63;
  const int lo = lane & 15, hi = lane >> 4;
  // XCD-aware decode: XCD x gets heads {4x..4x+3}; large-qi blocks first.
  const int flat = blockIdx.x + blockIdx.y * gridDim.x;  // 512 blocks
  const int j = flat >> 3;
  const int bh = (flat & 7) * 4 + (j & 3);
  const int qi = 15 - (j >> 2);
  const int b = bh >> 4, h = bh & 15;
  const int q0 = qi * 128;
  const int qw = q0 + wid * 32;  // this wave's 32 q-rows

  // ---- Q fragments (persistent) ----
  bf16x8 qhf[4][2], qlf[4][2];
  {
    const size_t qbase =
        (size_t)(b * kSeq + qw + lo) * kDModel + h * kDk + hi * 8;
#pragma unroll
    for (int qt = 0; qt < 2; ++qt)
#pragma unroll
      for (int ks = 0; ks < 4; ++ks) {
        const size_t o = qbase + (size_t)qt * 16 * kDModel + ks * 32;
        qhf[ks][qt] = *(const bf16x8*)(Qh + o);
        qlf[ks][qt] = *(const bf16x8*)(Ql + o);
      }
  }

  // ---- staging addresses (lane-constant; advance by fixed stride/tile) ----
  const int rK = wid * 8 + (lane >> 4);           // K row (i=0); i=1 adds 4
  const int gK0 = ((lane & 15) ^ (rK & 7)) * 8;   // swizzled chunk offset
  const bf16_t* pKh0 = Kh + (size_t)(b * kSeq + rK) * kDModel + h * kDk + gK0;
  const bf16_t* pKh1 = pKh0 + (size_t)4 * kDModel + ((gK0 ^ 32) - gK0);
  const bf16_t* pKl0 = Kl + (pKh0 - Kh);
  const bf16_t* pKl1 = Kl + (pKh1 - Kh);
  const int dV = wid * 32 + (lane >> 2);          // V d-row (i=0); i=1 adds 16
  const int gV = ((lane & 3) ^ ((dV >> 1) & 3)) * 8;
  const bf16_t* pV0 = VT + (size_t)(bh * kDk + dV) * kSeq + gV;
  const bf16_t* pV1 = pV0 + (size_t)16 * kSeq;
  const int ldsK = (wid * 8) * 128;               // this wave's K dest (i=0)
  const int ldsV = (wid * 32) * 32;               // this wave's V dest (i=0)

  f32x4 of[8][2];
  const f32x4 z = {0.f, 0.f, 0.f, 0.f};
#pragma unroll
  for (int di = 0; di < 8; ++di) {
    of[di][0] = z;
    of[di][1] = z;
  }
  float m[2] = {-3e38f, -3e38f};
  float l[2] = {0.f, 0.f};

  const int nkv = 4 * qi + 4;  // 32-key tiles

  auto STAGE = [&](int buf, int t) {
    const size_t ko = (size_t)t * 32 * kDModel;
    const size_t vo = (size_t)t * 32;
    bf16_t* dk = sK[buf][0] + ldsK;
    bf16_t* dl = sK[buf][1] + ldsK;
    gload_lds16(pKh0 + ko, dk);
    gload_lds16(pKh1 + ko, dk + 512);
    gload_lds16(pKl0 + ko, dl);
    gload_lds16(pKl1 + ko, dl + 512);
    bf16_t* dv = sV[buf] + ldsV;
    gload_lds16(pV0 + vo, dv);
    gload_lds16(pV1 + vo, dv + 512);
  };

  STAGE(0, 0);
  __syncthreads();

  for (int t = 0; t < nkv; ++t) {
    const int kv0 = t * 32;
    if (t + 1 < nkv) STAGE((t + 1) & 1, t + 1);

    if (kv0 <= qw + 31) {  // skip tiles fully masked for this wave
      const bf16_t* bKh = sK[t & 1][0];
      const bf16_t* bKl = sK[t & 1][1];
      const bf16_t* bV = sV[t & 1];
      const bool maskedw = (kv0 + 31 > qw);

      // ---- QK^T (3-term split) ----
      f32x4 st[2][2];
      st[0][0] = z; st[0][1] = z; st[1][0] = z; st[1][1] = z;
#pragma unroll
      for (int kt = 0; kt < 2; ++kt) {
#pragma unroll
        for (int ks = 0; ks < 4; ++ks) {
          const int krow = kt * 16 + lo;
          const int ka = krow * 128 + (((ks * 4 + hi) ^ (krow & 7)) * 8);
          const bf16x8 kh8 = *(const bf16x8*)(bKh + ka);
          const bf16x8 kl8 = *(const bf16x8*)(bKl + ka);
#pragma unroll
          for (int qt = 0; qt < 2; ++qt) {
            st[kt][qt] = mfma32(kh8, qhf[ks][qt], st[kt][qt]);
            st[kt][qt] = mfma32(kh8, qlf[ks][qt], st[kt][qt]);
            st[kt][qt] = mfma32(kl8, qhf[ks][qt], st[kt][qt]);
          }
        }
      }

      // ---- online softmax per q column ----
      bf16x4 pb[2][2];
#pragma unroll
      for (int qt = 0; qt < 2; ++qt) {
        const int q = qw + qt * 16 + lo;
        float mt = -3e38f;
#pragma unroll
        for (int kt = 0; kt < 2; ++kt)
#pragma unroll
          for (int r = 0; r < 4; ++r) {
            float s = st[kt][qt][r];
            if (maskedw && (kv0 + kt * 16 + hi * 4 + r > q)) s = -1e30f;
            st[kt][qt][r] = s;
            mt = fmaxf(mt, s);
          }
        mt = fmaxf(mt, __shfl_xor(mt, 16));
        mt = fmaxf(mt, __shfl_xor(mt, 32));
        const float mnew = fmaxf(m[qt], mt);
        const float corr = __expf(m[qt] - mnew);
        float rs = 0.f;
#pragma unroll
        for (int kt = 0; kt < 2; ++kt) {
          bf16x4 pv;
#pragma unroll
          for (int r = 0; r < 4; ++r) {
            const float pp = __expf(st[kt][qt][r] - mnew);
            rs += pp;
            pv[r] = (bf16_t)pp;
          }
          pb[kt][qt] = pv;
        }
        rs += __shfl_xor(rs, 16);
        rs += __shfl_xor(rs, 32);
        l[qt] = l[qt] * corr + rs;
        m[qt] = mnew;
#pragma unroll
        for (int di = 0; di < 8; ++di) of[di][qt] = of[di][qt] * corr;
      }

      // ---- PV: of[d][q] += V^T * P^T ----
#pragma unroll
      for (int di = 0; di < 8; ++di) {
        const int d = di * 16 + lo;
#pragma unroll
        for (int kt = 0; kt < 2; ++kt) {
          const int c = (kt * 2 + (hi >> 1)) ^ ((d >> 1) & 3);
          const bf16x4 vf = *(const bf16x4*)(bV + d * 32 + c * 8 + (hi & 1) * 4);
          of[di][0] = mfma16(vf, pb[kt][0], of[di][0]);
          of[di][1] = mfma16(vf, pb[kt][1], of[di][1]);
        }
      }
    }
    __syncthreads();
  }

  // ---- epilogue: O^T fragments -> Ob[b][q][h*128+d] ----
#pragma unroll
  for (int qt = 0; qt < 2; ++qt) {
    const float linv = 1.f / l[qt];
    const size_t ob =
        (size_t)(b * kSeq + qw + qt * 16 + lo) * kDModel + h * kDk + hi * 4;
#pragma unroll
    for (int di = 0; di < 8; ++di) {
      bf16x4 ov;
#pragma unroll
      for (int r = 0; r < 4; ++r) ov[r] = (bf16_t)(of[di][qt][r] * linv);
      *(bf16x4*)(Ob + ob + di * 16) = ov;
    }
  }
}

}  // namespace

extern "C" void kernel_launch(void* const* d_in, const int* in_sizes, int n_in,
                              void* d_out, int out_size, void* d_ws, size_t ws_size,
                              hipStream_t stream) {
  (void)in_sizes; (void)n_in; (void)out_size;
  const float* x = (const float*)d_in[0];
  const int* tokpos = (const int*)d_in[1];
  const float* wq = (const float*)d_in[2];
  const float* wk = (const float*)d_in[3];
  const float* wv = (const float*)d_in[4];
  const float* wo = (const float*)d_in[5];
  float* out = (float*)d_out;

  char* p = (char*)d_ws;
  auto take = [&](size_t bytes) { char* q = p; p += bytes; return q; };
  float* cost = (float*)take((size_t)kSeq * 64 * sizeof(float));
  float* sint = (float*)take((size_t)kSeq * 64 * sizeof(float));
  const size_t mat = (size_t)kM * kDModel * sizeof(bf16_t);        // 16.8 MB
  const size_t wmat = (size_t)kDModel * kDModel * sizeof(bf16_t);  // 8.4 MB
  bf16_t* xh = (bf16_t*)take(mat);
  bf16_t* xl = (bf16_t*)take(mat);
  bf16_t* wqth = (bf16_t*)take(wmat);
  bf16_t* wqtl = (bf16_t*)take(wmat);
  bf16_t* wkth = (bf16_t*)take(wmat);
  bf16_t* wktl = (bf16_t*)take(wmat);
  bf16_t* wvt = (bf16_t*)take(wmat);
  bf16_t* wot = (bf16_t*)take(wmat);
  bf16_t* qh = (bf16_t*)take(mat);
  bf16_t* ql = (bf16_t*)take(mat);
  bf16_t* kh = (bf16_t*)take(mat);
  bf16_t* kl = (bf16_t*)take(mat);
  bf16_t* vt = (bf16_t*)take(mat);
  bf16_t* ob = (bf16_t*)take(mat);
  if ((size_t)(p - (char*)d_ws) > ws_size) {
    fprintf(stderr, "MHA: workspace too small: need %zu have %zu\n",
            (size_t)(p - (char*)d_ws), ws_size);
    return;
  }

  k_rope_table<<<dim3(kSeq), dim3(64), 0, stream>>>(cost, sint);
  k_split_x<<<dim3((kM * kDModel) / (256 * 4)), dim3(256), 0, stream>>>(
      x, xh, xl, kM * kDModel);
  {
    dim3 tb(32, 8), tg(kDModel / 32, kDModel / 32);
    k_transpose_w<<<tg, tb, 0, stream>>>(wq, wqth, wqtl);
    k_transpose_w<<<tg, tb, 0, stream>>>(wk, wkth, wktl);
    k_transpose_w<<<tg, tb, 0, stream>>>(wv, wvt, nullptr);
    k_transpose_w<<<tg, tb, 0, stream>>>(wo, wot, nullptr);
  }
  const dim3 gg(kDModel / 128, kM / 128);
  k_gemm<3, 1><<<gg, 256, 0, stream>>>(xh, xl, wqth, wqtl, qh, ql, tokpos, cost,
                                       sint, kQScale, kM, kDModel, kDModel);
  k_gemm<3, 1><<<gg, 256, 0, stream>>>(xh, xl, wkth, wktl, kh, kl, tokpos, cost,
                                       sint, 1.0f, kM, kDModel, kDModel);
  k_gemm<1, 2><<<gg, 256, 0, stream>>>(xh, nullptr, wvt, nullptr, vt, nullptr,
                                       nullptr, nullptr, nullptr, 1.0f, kM,
                                       kDModel, kDModel);
  k_attn3<<<dim3(kSeq / 128, kBatch * kHeads), dim3(256), 0, stream>>>(
      qh, ql, kh, kl, vt, ob);
  k_gemm<1, 0><<<gg, 256, 0, stream>>>(ob, nullptr, wot, nullptr, out, nullptr,
                                       nullptr, nullptr, nullptr, 1.0f, kM,
                                       kDModel, kDModel);
}

// Round 4
// 467.399 us; speedup vs baseline: 2.6435x; 1.0945x over previous
//
#include <hip/hip_runtime.h>
#include <hip/hip_bf16.h>
#include <cstdio>

namespace {

constexpr int kSeq = 2048;
constexpr int kDModel = 2048;
constexpr int kHeads = 16;
constexpr int kDk = 128;
constexpr int kBatch = 2;
constexpr int kM = kBatch * kSeq;  // 4096 rows of x
constexpr float kQScale = 0.08838834764831845f;  // 1/sqrt(128)

typedef __bf16 bf16_t;
typedef __bf16 bf16x8 __attribute__((ext_vector_type(8)));
typedef __bf16 bf16x4 __attribute__((ext_vector_type(4)));
typedef float f32x4 __attribute__((ext_vector_type(4)));
typedef short s16x4 __attribute__((ext_vector_type(4)));

__device__ __forceinline__ f32x4 mfma32(bf16x8 a, bf16x8 b, f32x4 c) {
  return __builtin_amdgcn_mfma_f32_16x16x32_bf16(a, b, c, 0, 0, 0);
}

#if __has_builtin(__builtin_amdgcn_mfma_f32_16x16x16_bf16)
__device__ __forceinline__ f32x4 mfma16(bf16x4 a, bf16x4 b, f32x4 c) {
  return __builtin_amdgcn_mfma_f32_16x16x16_bf16(a, b, c, 0, 0, 0);
}
#else
__device__ __forceinline__ f32x4 mfma16(bf16x4 a, bf16x4 b, f32x4 c) {
  union U { bf16x4 b; s16x4 s; } ua, ub;
  ua.b = a; ub.b = b;
  return __builtin_amdgcn_mfma_f32_16x16x16bf16_1k(ua.s, ub.s, c, 0, 0, 0);
}
#endif

using gas_void = const __attribute__((address_space(1))) void;
using las_void = __attribute__((address_space(3))) void;

__device__ __forceinline__ void gload_lds16(const bf16_t* g, bf16_t* l) {
  __builtin_amdgcn_global_load_lds((gas_void*)g, (las_void*)l, 16, 0, 0);
}

// ---------------- RoPE table (fp64 for max fidelity vs np reference) --------
__global__ void k_rope_table(float* __restrict__ cost, float* __restrict__ sint) {
  const int p = blockIdx.x;
  const int i = threadIdx.x;
  const double inv = exp(-(double)(2 * i) * 9.210340371976184 / 128.0);
  const double ang = (double)p * inv;
  cost[p * 64 + i] = (float)cos(ang);
  sint[p * 64 + i] = (float)sin(ang);
}

// ---------------- x -> (hi,lo) bf16 split -----------------------------------
__global__ void k_split_x(const float* __restrict__ x, bf16_t* __restrict__ xh,
                          bf16_t* __restrict__ xl, int n) {
  const int idx = (blockIdx.x * blockDim.x + threadIdx.x) * 4;
  if (idx >= n) return;
  const float4 v = *(const float4*)(x + idx);
  const float vv[4] = {v.x, v.y, v.z, v.w};
  bf16x4 hv, lv;
#pragma unroll
  for (int j = 0; j < 4; ++j) {
    const bf16_t h = (bf16_t)vv[j];
    hv[j] = h;
    lv[j] = (bf16_t)(vv[j] - (float)h);
  }
  *(bf16x4*)(xh + idx) = hv;
  *(bf16x4*)(xl + idx) = lv;
}

// ---------------- W (fp32 [K][N]) -> W^T bf16 hi(/lo) [N][K] ----------------
__global__ void k_transpose_w(const float* __restrict__ w, bf16_t* __restrict__ wth,
                              bf16_t* __restrict__ wtl) {
  __shared__ float tile[32][33];
  const int bx = blockIdx.x * 32;  // n
  const int by = blockIdx.y * 32;  // k
  const int tx = threadIdx.x, ty = threadIdx.y;
#pragma unroll
  for (int i = 0; i < 32; i += 8)
    tile[ty + i][tx] = w[(size_t)(by + ty + i) * kDModel + bx + tx];
  __syncthreads();
#pragma unroll
  for (int i = 0; i < 32; i += 8) {
    const float v = tile[tx][ty + i];
    const size_t o = (size_t)(bx + ty + i) * kDModel + by + tx;
    const bf16_t h = (bf16_t)v;
    wth[o] = h;
    if (wtl) wtl[o] = (bf16_t)(v - (float)h);
  }
}

// ---------------- Tiled MFMA GEMM: C = A @ B (B given transposed [N][K]) ----
// TERMS==3: C = Ah*Bh + Ah*Bl + Al*Bh (split-bf16 ~fp32 accuracy)
// EPI: 0 = store fp32 row-major; 1 = RoPE + split-bf16 store (Q/K);
//      2 = store bf16 V^T per head [bh*128+d][s]
template <int TERMS, int EPI>
__global__ __launch_bounds__(256) void k_gemm(
    const bf16_t* __restrict__ Ah, const bf16_t* __restrict__ Al,
    const bf16_t* __restrict__ Bh, const bf16_t* __restrict__ Bl,
    void* __restrict__ O0, void* __restrict__ O1,
    const int* __restrict__ tokpos, const float* __restrict__ cost,
    const float* __restrict__ sint, float scale, int M, int N, int K) {
  __shared__ __align__(16) bf16_t sAh[128 * 32];
  __shared__ __align__(16) bf16_t sBh[128 * 32];
  __shared__ __align__(16) bf16_t sAl[TERMS == 3 ? 128 * 32 : 8];
  __shared__ __align__(16) bf16_t sBl[TERMS == 3 ? 128 * 32 : 8];

  const int tid = threadIdx.x;
  const int wid = tid >> 6;
  const int lane = tid & 63;
  const int lo = lane & 15, hi = lane >> 4;
  const int wr = wid >> 1, wc = wid & 1;
  // m204-bijective XCD swizzle (total blocks divisible by 8)
  const int flat = blockIdx.x + blockIdx.y * gridDim.x;
  const int wgid = (flat & 7) * ((gridDim.x * gridDim.y) >> 3) + (flat >> 3);
  const int m0 = (wgid / gridDim.x) * 128, n0 = (wgid % gridDim.x) * 128;

  f32x4 acc[4][4];
  const f32x4 z = {0.f, 0.f, 0.f, 0.f};
#pragma unroll
  for (int i = 0; i < 4; ++i)
#pragma unroll
    for (int j = 0; j < 4; ++j) acc[i][j] = z;

  const int rr = wid * 16 + (lane >> 2);  // staging row (chunk 0)
  const int kk = (lane & 3) * 8;          // staging k offset

  for (int k0 = 0; k0 < K; k0 += 32) {
    __syncthreads();
    {
      const bf16_t* gA = Ah + (size_t)(m0 + rr) * K + k0 + kk;
      gload_lds16(gA, sAh + wid * 512);
      gload_lds16(gA + (size_t)64 * K, sAh + 2048 + wid * 512);
      const bf16_t* gB = Bh + (size_t)(n0 + rr) * K + k0 + kk;
      gload_lds16(gB, sBh + wid * 512);
      gload_lds16(gB + (size_t)64 * K, sBh + 2048 + wid * 512);
      if constexpr (TERMS == 3) {
        const bf16_t* gAl = Al + (size_t)(m0 + rr) * K + k0 + kk;
        gload_lds16(gAl, sAl + wid * 512);
        gload_lds16(gAl + (size_t)64 * K, sAl + 2048 + wid * 512);
        const bf16_t* gBl = Bl + (size_t)(n0 + rr) * K + k0 + kk;
        gload_lds16(gBl, sBl + wid * 512);
        gload_lds16(gBl + (size_t)64 * K, sBl + 2048 + wid * 512);
      }
    }
    __syncthreads();
    bf16x8 fah[4], fbh[4];
#pragma unroll
    for (int mi = 0; mi < 4; ++mi)
      fah[mi] = *(const bf16x8*)(sAh + (wr * 64 + mi * 16 + lo) * 32 + 8 * hi);
#pragma unroll
    for (int ni = 0; ni < 4; ++ni)
      fbh[ni] = *(const bf16x8*)(sBh + (wc * 64 + ni * 16 + lo) * 32 + 8 * hi);
    if constexpr (TERMS == 3) {
      bf16x8 fal[4], fbl[4];
#pragma unroll
      for (int mi = 0; mi < 4; ++mi)
        fal[mi] = *(const bf16x8*)(sAl + (wr * 64 + mi * 16 + lo) * 32 + 8 * hi);
#pragma unroll
      for (int ni = 0; ni < 4; ++ni)
        fbl[ni] = *(const bf16x8*)(sBl + (wc * 64 + ni * 16 + lo) * 32 + 8 * hi);
#pragma unroll
      for (int mi = 0; mi < 4; ++mi)
#pragma unroll
        for (int ni = 0; ni < 4; ++ni) {
          acc[mi][ni] = mfma32(fah[mi], fbh[ni], acc[mi][ni]);
          acc[mi][ni] = mfma32(fah[mi], fbl[ni], acc[mi][ni]);
          acc[mi][ni] = mfma32(fal[mi], fbh[ni], acc[mi][ni]);
        }
    } else {
#pragma unroll
      for (int mi = 0; mi < 4; ++mi)
#pragma unroll
        for (int ni = 0; ni < 4; ++ni)
          acc[mi][ni] = mfma32(fah[mi], fbh[ni], acc[mi][ni]);
    }
  }

  if constexpr (EPI == 0) {
    float* C = (float*)O0;
#pragma unroll
    for (int mi = 0; mi < 4; ++mi)
#pragma unroll
      for (int ni = 0; ni < 4; ++ni)
#pragma unroll
        for (int r = 0; r < 4; ++r) {
          const int row = m0 + wr * 64 + mi * 16 + hi * 4 + r;
          const int col = n0 + wc * 64 + ni * 16 + lo;
          C[(size_t)row * N + col] = acc[mi][ni][r];
        }
  } else if constexpr (EPI == 1) {
    bf16_t* Xh = (bf16_t*)O0;
    bf16_t* Xl = (bf16_t*)O1;
    const int is64 = (tokpos[1] == 0) ? 1 : 0;  // int64 positions -> high word 0
#pragma unroll
    for (int mi = 0; mi < 4; ++mi) {
#pragma unroll
      for (int r = 0; r < 4; ++r) {
        const int row = m0 + wr * 64 + mi * 16 + hi * 4 + r;
        const int pos = is64 ? tokpos[2 * row] : tokpos[row];
#pragma unroll
        for (int ni = 0; ni < 4; ++ni) {
          const int col = n0 + wc * 64 + ni * 16 + lo;
          const float v = acc[mi][ni][r] * scale;
          const float pv = __shfl_xor(v, 1);  // paired column (col^1)
          const int ip = (col & 127) >> 1;
          const float c = cost[pos * 64 + ip];
          const float sn = sint[pos * 64 + ip];
          const float sgn = (lo & 1) ? sn : -sn;  // even: -x_o*s ; odd: +x_e*s
          const float rv = v * c + pv * sgn;
          const bf16_t hb = (bf16_t)rv;
          const size_t o = (size_t)row * N + col;
          Xh[o] = hb;
          Xl[o] = (bf16_t)(rv - (float)hb);
        }
      }
    }
  } else {  // EPI == 2 : V^T
    bf16_t* VT = (bf16_t*)O0;
#pragma unroll
    for (int mi = 0; mi < 4; ++mi)
#pragma unroll
      for (int ni = 0; ni < 4; ++ni) {
        const int col = n0 + wc * 64 + ni * 16 + lo;
        const int h = col >> 7, d = col & 127;
        const int rowb = m0 + wr * 64 + mi * 16 + hi * 4;
        const int b = rowb >> 11, s = rowb & (kSeq - 1);
        bf16x4 ov;
#pragma unroll
        for (int r = 0; r < 4; ++r) ov[r] = (bf16_t)acc[mi][ni][r];
        *(bf16x4*)(VT + ((size_t)((b * kHeads + h) * kDk + d)) * kSeq + s) = ov;
      }
  }
}

// ---------------- Causal flash attention, strip-paired, 8 waves -------------
// 256 blocks (1/CU, no tail): block = (bh, p). Waves 0-3 -> strip qi=15-p,
// waves 4-7 -> strip qi=p (32 q-rows/wave). Work/block uniform (36 units).
// KV tile = 64 keys, double-buffered LDS (96 KB):
//   sK[buf][h/l] [64][128]: 16B chunks swizzled chunk^(row&15)
//   sV[buf]      [128][64]: 16B chunks swizzled chunk^(d&7)
// STAGE(next) issued before compute(cur); one barrier/tile drains vmcnt.
// T13 defer-rescale: skip of-rescale while tile max <= m+8 (P <= e^8).
__global__ __launch_bounds__(512, 2) void k_attn4(
    const bf16_t* __restrict__ Qh, const bf16_t* __restrict__ Ql,
    const bf16_t* __restrict__ Kh, const bf16_t* __restrict__ Kl,
    const bf16_t* __restrict__ VT, bf16_t* __restrict__ Ob) {
  __shared__ __align__(16) bf16_t sK[2][2][64 * 128];
  __shared__ __align__(16) bf16_t sV[2][128 * 64];

  const int tid = threadIdx.x;
  const int wid = tid >> 6, lane = tid & 63;
  const int lo = lane & 15, hi = lane >> 4;
  const int flat = blockIdx.x;  // 256 blocks
  const int j = flat >> 3;
  const int bh = (flat & 7) * 4 + (j & 3);  // XCD x -> heads 4x..4x+3
  const int p = j >> 2;                     // 0..7
  const int b = bh >> 4, h = bh & 15;
  const int qiW = (wid < 4) ? (15 - p) : p;
  const int qw = qiW * 128 + (wid & 3) * 32;  // this wave's 32 q-rows
  const int nkv = 2 * (15 - p) + 2;           // 64-key tiles staged

  // ---- Q fragments (persistent) ----
  bf16x8 qhf[4][2], qlf[4][2];
  {
    const size_t qbase =
        (size_t)(b * kSeq + qw + lo) * kDModel + h * kDk + hi * 8;
#pragma unroll
    for (int qt = 0; qt < 2; ++qt)
#pragma unroll
      for (int ks = 0; ks < 4; ++ks) {
        const size_t o = qbase + (size_t)qt * 16 * kDModel + ks * 32;
        qhf[ks][qt] = *(const bf16x8*)(Qh + o);
        qlf[ks][qt] = *(const bf16x8*)(Ql + o);
      }
  }

  // ---- staging addresses (lane-constant; advance by fixed stride/tile) ----
  const int rK0 = wid * 8 + (lane >> 4);          // K local row, op 0 (+4 op 1)
  const int gK0 = ((lane & 15) ^ (rK0 & 15)) * 8;
  const int gK1 = ((lane & 15) ^ ((rK0 + 4) & 15)) * 8;
  const bf16_t* pKh0 = Kh + (size_t)(b * kSeq + rK0) * kDModel + h * kDk + gK0;
  const bf16_t* pKh1 = Kh + (size_t)(b * kSeq + rK0 + 4) * kDModel + h * kDk + gK1;
  const bf16_t* pKl0 = Kl + (pKh0 - Kh);
  const bf16_t* pKl1 = Kl + (pKh1 - Kh);
  const int dV0 = wid * 16 + (lane >> 3);         // V local d-row, op 0 (+8 op 1)
  const int gV0 = ((lane & 7) ^ (dV0 & 7)) * 8;
  const int gV1 = ((lane & 7) ^ ((dV0 + 8) & 7)) * 8;
  const bf16_t* pV0 = VT + (size_t)(bh * kDk + dV0) * kSeq + gV0;
  const bf16_t* pV1 = VT + (size_t)(bh * kDk + dV0 + 8) * kSeq + gV1;
  const int ldsK = (wid * 8) * 128;   // this wave's K dest (op 0; op 1 +512)
  const int ldsV = (wid * 16) * 64;   // this wave's V dest (op 0; op 1 +512)

  f32x4 of[8][2];
  const f32x4 z = {0.f, 0.f, 0.f, 0.f};
#pragma unroll
  for (int di = 0; di < 8; ++di) {
    of[di][0] = z;
    of[di][1] = z;
  }
  float m[2] = {-3e38f, -3e38f};
  float l[2] = {0.f, 0.f};

  auto STAGE = [&](int buf, int t) {
    const size_t ko = (size_t)t * 64 * kDModel;
    const size_t vo = (size_t)t * 64;
    bf16_t* dk = sK[buf][0] + ldsK;
    bf16_t* dl = sK[buf][1] + ldsK;
    gload_lds16(pKh0 + ko, dk);
    gload_lds16(pKh1 + ko, dk + 512);
    gload_lds16(pKl0 + ko, dl);
    gload_lds16(pKl1 + ko, dl + 512);
    bf16_t* dv = sV[buf] + ldsV;
    gload_lds16(pV0 + vo, dv);
    gload_lds16(pV1 + vo, dv + 512);
  };

  STAGE(0, 0);
  __syncthreads();

  for (int t = 0; t < nkv; ++t) {
    const int kv0 = t * 64;
    if (t + 1 < nkv) STAGE((t + 1) & 1, t + 1);

    if (kv0 <= qw + 31) {  // skip tiles fully masked for this wave
      const bf16_t* bKh = sK[t & 1][0];
      const bf16_t* bKl = sK[t & 1][1];
      const bf16_t* bV = sV[t & 1];
      const bool maskedw = (kv0 + 63 > qw);

      // ---- QK^T (3-term split) ----
      f32x4 st[4][2];
#pragma unroll
      for (int kt = 0; kt < 4; ++kt) {
        st[kt][0] = z;
        st[kt][1] = z;
      }
#pragma unroll
      for (int kt = 0; kt < 4; ++kt) {
#pragma unroll
        for (int ks = 0; ks < 4; ++ks) {
          const int krow = kt * 16 + lo;
          const int ka = krow * 128 + (((ks * 4 + hi) ^ (krow & 15)) * 8);
          const bf16x8 kh8 = *(const bf16x8*)(bKh + ka);
          const bf16x8 kl8 = *(const bf16x8*)(bKl + ka);
#pragma unroll
          for (int qt = 0; qt < 2; ++qt) {
            st[kt][qt] = mfma32(kh8, qhf[ks][qt], st[kt][qt]);
            st[kt][qt] = mfma32(kh8, qlf[ks][qt], st[kt][qt]);
            st[kt][qt] = mfma32(kl8, qhf[ks][qt], st[kt][qt]);
          }
        }
      }

      // ---- online softmax per q column (lane's column = lo) ----
      bf16x4 pb[4][2];
#pragma unroll
      for (int qt = 0; qt < 2; ++qt) {
        const int q = qw + qt * 16 + lo;
        float mt = -3e38f;
#pragma unroll
        for (int kt = 0; kt < 4; ++kt)
#pragma unroll
          for (int r = 0; r < 4; ++r) {
            float s = st[kt][qt][r];
            if (maskedw && (kv0 + kt * 16 + hi * 4 + r > q)) s = -1e30f;
            st[kt][qt][r] = s;
            mt = fmaxf(mt, s);
          }
        mt = fmaxf(mt, __shfl_xor(mt, 16));
        mt = fmaxf(mt, __shfl_xor(mt, 32));
        if (!__all(mt <= m[qt] + 8.f)) {  // T13: rescale only when max grows
          const float mnew = fmaxf(m[qt], mt);
          const float corr = __expf(m[qt] - mnew);
          l[qt] *= corr;
#pragma unroll
          for (int di = 0; di < 8; ++di) of[di][qt] = of[di][qt] * corr;
          m[qt] = mnew;
        }
        float rs = 0.f;
#pragma unroll
        for (int kt = 0; kt < 4; ++kt) {
          bf16x4 pv;
#pragma unroll
          for (int r = 0; r < 4; ++r) {
            const float pp = __expf(st[kt][qt][r] - m[qt]);
            rs += pp;
            pv[r] = (bf16_t)pp;
          }
          pb[kt][qt] = pv;
        }
        rs += __shfl_xor(rs, 16);
        rs += __shfl_xor(rs, 32);
        l[qt] += rs;
      }

      // ---- PV: of[d][q] += V^T * P^T ----
#pragma unroll
      for (int di = 0; di < 8; ++di) {
        const int d = di * 16 + lo;
#pragma unroll
        for (int kt = 0; kt < 4; ++kt) {
          const int va =
              d * 64 + (((kt * 2 + (hi >> 1)) ^ (d & 7)) * 8) + (hi & 1) * 4;
          const bf16x4 vf = *(const bf16x4*)(bV + va);
          of[di][0] = mfma16(vf, pb[kt][0], of[di][0]);
          of[di][1] = mfma16(vf, pb[kt][1], of[di][1]);
        }
      }
    }
    __syncthreads();
  }

  // ---- epilogue: O^T fragments -> Ob[b][q][h*128+d] ----
#pragma unroll
  for (int qt = 0; qt < 2; ++qt) {
    const float linv = 1.f / l[qt];
    const size_t ob =
        (size_t)(b * kSeq + qw + qt * 16 + lo) * kDModel + h * kDk + hi * 4;
#pragma unroll
    for (int di = 0; di < 8; ++di) {
      bf16x4 ov;
#pragma unroll
      for (int r = 0; r < 4; ++r) ov[r] = (bf16_t)(of[di][qt][r] * linv);
      *(bf16x4*)(Ob + ob + di * 16) = ov;
    }
  }
}

}  // namespace

extern "C" void kernel_launch(void* const* d_in, const int* in_sizes, int n_in,
                              void* d_out, int out_size, void* d_ws, size_t ws_size,
                              hipStream_t stream) {
  (void)in_sizes; (void)n_in; (void)out_size;
  const float* x = (const float*)d_in[0];
  const int* tokpos = (const int*)d_in[1];
  const float* wq = (const float*)d_in[2];
  const float* wk = (const float*)d_in[3];
  const float* wv = (const float*)d_in[4];
  const float* wo = (const float*)d_in[5];
  float* out = (float*)d_out;

  char* p = (char*)d_ws;
  auto take = [&](size_t bytes) { char* q = p; p += bytes; return q; };
  float* cost = (float*)take((size_t)kSeq * 64 * sizeof(float));
  float* sint = (float*)take((size_t)kSeq * 64 * sizeof(float));
  const size_t mat = (size_t)kM * kDModel * sizeof(bf16_t);        // 16.8 MB
  const size_t wmat = (size_t)kDModel * kDModel * sizeof(bf16_t);  // 8.4 MB
  bf16_t* xh = (bf16_t*)take(mat);
  bf16_t* xl = (bf16_t*)take(mat);
  bf16_t* wqth = (bf16_t*)take(wmat);
  bf16_t* wqtl = (bf16_t*)take(wmat);
  bf16_t* wkth = (bf16_t*)take(wmat);
  bf16_t* wktl = (bf16_t*)take(wmat);
  bf16_t* wvt = (bf16_t*)take(wmat);
  bf16_t* wot = (bf16_t*)take(wmat);
  bf16_t* qh = (bf16_t*)take(mat);
  bf16_t* ql = (bf16_t*)take(mat);
  bf16_t* kh = (bf16_t*)take(mat);
  bf16_t* kl = (bf16_t*)take(mat);
  bf16_t* vt = (bf16_t*)take(mat);
  bf16_t* ob = (bf16_t*)take(mat);
  if ((size_t)(p - (char*)d_ws) > ws_size) {
    fprintf(stderr, "MHA: workspace too small: need %zu have %zu\n",
            (size_t)(p - (char*)d_ws), ws_size);
    return;
  }

  k_rope_table<<<dim3(kSeq), dim3(64), 0, stream>>>(cost, sint);
  k_split_x<<<dim3((kM * kDModel) / (256 * 4)), dim3(256), 0, stream>>>(
      x, xh, xl, kM * kDModel);
  {
    dim3 tb(32, 8), tg(kDModel / 32, kDModel / 32);
    k_transpose_w<<<tg, tb, 0, stream>>>(wq, wqth, wqtl);
    k_transpose_w<<<tg, tb, 0, stream>>>(wk, wkth, wktl);
    k_transpose_w<<<tg, tb, 0, stream>>>(wv, wvt, nullptr);
    k_transpose_w<<<tg, tb, 0, stream>>>(wo, wot, nullptr);
  }
  const dim3 gg(kDModel / 128, kM / 128);
  k_gemm<3, 1><<<gg, 256, 0, stream>>>(xh, xl, wqth, wqtl, qh, ql, tokpos, cost,
                                       sint, kQScale, kM, kDModel, kDModel);
  k_gemm<3, 1><<<gg, 256, 0, stream>>>(xh, xl, wkth, wktl, kh, kl, tokpos, cost,
                                       sint, 1.0f, kM, kDModel, kDModel);
  k_gemm<1, 2><<<gg, 256, 0, stream>>>(xh, nullptr, wvt, nullptr, vt, nullptr,
                                       nullptr, nullptr, nullptr, 1.0f, kM,
                                       kDModel, kDModel);
  k_attn4<<<dim3(256), dim3(512), 0, stream>>>(qh, ql, kh, kl, vt, ob);
  k_gemm<1, 0><<<gg, 256, 0, stream>>>(ob, nullptr, wot, nullptr, out, nullptr,
                                       nullptr, nullptr, nullptr, 1.0f, kM,
                                       kDModel, kDModel);
}

// Round 5
// 437.451 us; speedup vs baseline: 2.8245x; 1.0685x over previous
//
#include <hip/hip_runtime.h>
#include <hip/hip_bf16.h>
#include <cstdio>

namespace {

constexpr int kSeq = 2048;
constexpr int kDModel = 2048;
constexpr int kHeads = 16;
constexpr int kDk = 128;
constexpr int kBatch = 2;
constexpr int kM = kBatch * kSeq;  // 4096 rows of x
constexpr float kQScale = 0.08838834764831845f;  // 1/sqrt(128)

typedef __bf16 bf16_t;
typedef __bf16 bf16x8 __attribute__((ext_vector_type(8)));
typedef __bf16 bf16x4 __attribute__((ext_vector_type(4)));
typedef float f32x4 __attribute__((ext_vector_type(4)));
typedef short s16x4 __attribute__((ext_vector_type(4)));

__device__ __forceinline__ f32x4 mfma32(bf16x8 a, bf16x8 b, f32x4 c) {
  return __builtin_amdgcn_mfma_f32_16x16x32_bf16(a, b, c, 0, 0, 0);
}

#if __has_builtin(__builtin_amdgcn_mfma_f32_16x16x16_bf16)
__device__ __forceinline__ f32x4 mfma16(bf16x4 a, bf16x4 b, f32x4 c) {
  return __builtin_amdgcn_mfma_f32_16x16x16_bf16(a, b, c, 0, 0, 0);
}
#else
__device__ __forceinline__ f32x4 mfma16(bf16x4 a, bf16x4 b, f32x4 c) {
  union U { bf16x4 b; s16x4 s; } ua, ub;
  ua.b = a; ub.b = b;
  return __builtin_amdgcn_mfma_f32_16x16x16bf16_1k(ua.s, ub.s, c, 0, 0, 0);
}
#endif

using gas_void = const __attribute__((address_space(1))) void;
using las_void = __attribute__((address_space(3))) void;

__device__ __forceinline__ void gload_lds16(const bf16_t* g, bf16_t* l) {
  __builtin_amdgcn_global_load_lds((gas_void*)g, (las_void*)l, 16, 0, 0);
}

// ---------------- RoPE table (fp64 for max fidelity vs np reference) --------
__global__ void k_rope_table(float* __restrict__ cost, float* __restrict__ sint) {
  const int p = blockIdx.x;
  const int i = threadIdx.x;
  const double inv = exp(-(double)(2 * i) * 9.210340371976184 / 128.0);
  const double ang = (double)p * inv;
  cost[p * 64 + i] = (float)cos(ang);
  sint[p * 64 + i] = (float)sin(ang);
}

// ---------------- x -> (hi,lo) bf16 split -----------------------------------
__global__ void k_split_x(const float* __restrict__ x, bf16_t* __restrict__ xh,
                          bf16_t* __restrict__ xl, int n) {
  const int idx = (blockIdx.x * blockDim.x + threadIdx.x) * 4;
  if (idx >= n) return;
  const float4 v = *(const float4*)(x + idx);
  const float vv[4] = {v.x, v.y, v.z, v.w};
  bf16x4 hv, lv;
#pragma unroll
  for (int j = 0; j < 4; ++j) {
    const bf16_t h = (bf16_t)vv[j];
    hv[j] = h;
    lv[j] = (bf16_t)(vv[j] - (float)h);
  }
  *(bf16x4*)(xh + idx) = hv;
  *(bf16x4*)(xl + idx) = lv;
}

// ---------------- W (fp32 [K][N]) -> W^T bf16 hi(/lo) [N][K] ----------------
__global__ void k_transpose_w(const float* __restrict__ w, bf16_t* __restrict__ wth,
                              bf16_t* __restrict__ wtl) {
  __shared__ float tile[32][33];
  const int bx = blockIdx.x * 32;  // n
  const int by = blockIdx.y * 32;  // k
  const int tx = threadIdx.x, ty = threadIdx.y;
#pragma unroll
  for (int i = 0; i < 32; i += 8)
    tile[ty + i][tx] = w[(size_t)(by + ty + i) * kDModel + bx + tx];
  __syncthreads();
#pragma unroll
  for (int i = 0; i < 32; i += 8) {
    const float v = tile[tx][ty + i];
    const size_t o = (size_t)(bx + ty + i) * kDModel + by + tx;
    const bf16_t h = (bf16_t)v;
    wth[o] = h;
    if (wtl) wtl[o] = (bf16_t)(v - (float)h);
  }
}

// ---------------- Ring-3 counted-vmcnt MFMA GEMM ----------------------------
// BM=256, BN=128, BK=64. 8 waves (4Mx2N), wave C = 64x64 (acc[4][4]).
// TERMS==3: segmented K' = [Ah,Ah,Al] x [Bh,Bl,Bh] (split-bf16 ~fp32), 96 tiles.
// LDS: 3-slot ring, per slot A 32KB (2 halves) + B 16KB (1 half) = 144 KB.
// Schedule per K-tile t (group): phase1 {ds A01+B0123, STAGE A(t+2), barrier,
// MFMA M01}, phase2 {ds A23, STAGE B(t+2), vmcnt(6), barrier, MFMA M23}.
// Ledger: stages issued in group g = 6 loads (tile g+2). vmcnt(6) at group-g
// exit leaves only tile g+2's 6 in flight => tile g+1 complete at entry of
// group g+1. Writes go to slot (t+2)%3, reads from slot t%3 -> never clash.
// Last 2 groups stage nothing; their exits use vmcnt(0).
// LDS swizzle (both sides, involution): chunk16 ^= (row & 7).
// EPI: 0 = fp32 store; 1 = fused Q|K RoPE split store (N=4096, col>>11 picks
//      Q vs K); 2 = bf16 V^T store [bh*128+d][s].
template <int TERMS, int EPI>
__global__ __launch_bounds__(512) void k_gemm8(
    const bf16_t* __restrict__ Ah, const bf16_t* __restrict__ Al,
    const bf16_t* __restrict__ Bh, const bf16_t* __restrict__ Bl,
    void* __restrict__ O0, void* __restrict__ O1, void* __restrict__ O2,
    void* __restrict__ O3, const int* __restrict__ tokpos,
    const float* __restrict__ cost, const float* __restrict__ sint, int NT,
    int ntk) {
  __shared__ __align__(16) bf16_t sA[3][256 * 64];
  __shared__ __align__(16) bf16_t sB[3][128 * 64];

  const int tid = threadIdx.x;
  const int wid = tid >> 6, lane = tid & 63;
  const int lo = lane & 15, hi = lane >> 4;
  const int wrr = wid >> 1, wcc = wid & 1;
  const int x7 = lo & 7;

  // XCD-bijective swizzle (gridDim.x % 8 == 0)
  const int bid = blockIdx.x;
  const int wgid = (bid & 7) * (gridDim.x >> 3) + (bid >> 3);
  const int mt = wgid / NT, nt = wgid % NT;
  const int m0 = mt * 256, n0 = nt * 128;

  // staging per-thread constants (source pre-swizzled: chunk ^ (row&7))
  const int rB = tid >> 3;                      // row within 64-row issue
  const int ch8 = ((tid & 7) ^ (rB & 7)) * 8;   // source chunk offset (elems)
  size_t offA[4], offB[2];
#pragma unroll
  for (int u = 0; u < 2; ++u)
#pragma unroll
    for (int i = 0; i < 2; ++i)
      offA[u * 2 + i] = (size_t)(m0 + u * 128 + i * 64 + rB) * 2048 + ch8;
#pragma unroll
  for (int i = 0; i < 2; ++i)
    offB[i] = (size_t)(n0 + i * 64 + rB) * 2048 + ch8;
  const int ldsOff = wid * 512;  // wave's dest inside each 4096-elem region

  auto STAGE_A = [&](int slot, int t) {
    const bf16_t* base;
    if constexpr (TERMS == 3)
      base = (t < 64 ? Ah : Al) + (t & 31) * 64;
    else
      base = Ah + t * 64;
    bf16_t* d = sA[slot] + ldsOff;
#pragma unroll
    for (int ui = 0; ui < 4; ++ui) gload_lds16(base + offA[ui], d + ui * 4096);
  };
  auto STAGE_B = [&](int slot, int t) {
    const bf16_t* base;
    if constexpr (TERMS == 3)
      base = (((t >> 5) == 1) ? Bl : Bh) + (t & 31) * 64;
    else
      base = Bh + t * 64;
    bf16_t* d = sB[slot] + ldsOff;
#pragma unroll
    for (int i = 0; i < 2; ++i) gload_lds16(base + offB[i], d + i * 4096);
  };

  // fragment LDS element offsets (row*64 + swizzled chunk*8)
  int aoff[4][2], boff[4][2];
#pragma unroll
  for (int mi = 0; mi < 4; ++mi)
#pragma unroll
    for (int ks = 0; ks < 2; ++ks)
      aoff[mi][ks] = (wrr * 64 + mi * 16 + lo) * 64 + (((ks * 4 + hi) ^ x7) * 8);
#pragma unroll
  for (int ni = 0; ni < 4; ++ni)
#pragma unroll
    for (int ks = 0; ks < 2; ++ks)
      boff[ni][ks] = (wcc * 64 + ni * 16 + lo) * 64 + (((ks * 4 + hi) ^ x7) * 8);

  f32x4 acc[4][4];
  const f32x4 z = {0.f, 0.f, 0.f, 0.f};
#pragma unroll
  for (int i = 0; i < 4; ++i)
#pragma unroll
    for (int j = 0; j < 4; ++j) acc[i][j] = z;

  // prologue: stage tiles 0 and 1; wait tile 0 (6 newest stay in flight)
  STAGE_A(0, 0);
  STAGE_B(0, 0);
  STAGE_A(1, 1);
  STAGE_B(1, 1);
  asm volatile("s_waitcnt vmcnt(6)" ::: "memory");
  __builtin_amdgcn_s_barrier();
  asm volatile("" ::: "memory");

  int s0 = 0;
  for (int t = 0; t < ntk; ++t) {
    const bf16_t* sa = sA[s0];
    const bf16_t* sb = sB[s0];
    int s2 = s0 + 2;
    if (s2 >= 3) s2 -= 3;
    const bool pf = (t + 2 < ntk);

    // ---- phase 1: reads for M01 + all B; stage next A; MFMA M01 ----
    bf16x8 af[2][2], bfr[4][2];
#pragma unroll
    for (int mi = 0; mi < 2; ++mi)
#pragma unroll
      for (int ks = 0; ks < 2; ++ks)
        af[mi][ks] = *(const bf16x8*)(sa + aoff[mi][ks]);
#pragma unroll
    for (int ni = 0; ni < 4; ++ni)
#pragma unroll
      for (int ks = 0; ks < 2; ++ks)
        bfr[ni][ks] = *(const bf16x8*)(sb + boff[ni][ks]);
    if (pf) STAGE_A(s2, t + 2);
    asm volatile("" ::: "memory");
    __builtin_amdgcn_s_barrier();
    asm volatile("" ::: "memory");
    __builtin_amdgcn_s_setprio(1);
#pragma unroll
    for (int ni = 0; ni < 4; ++ni)
#pragma unroll
      for (int mi = 0; mi < 2; ++mi)
#pragma unroll
        for (int ks = 0; ks < 2; ++ks)
          acc[mi][ni] = mfma32(af[mi][ks], bfr[ni][ks], acc[mi][ni]);
    __builtin_amdgcn_s_setprio(0);

    // ---- phase 2: reads for M23; stage next B; group-exit wait; MFMA M23 ----
    bf16x8 ag[2][2];
#pragma unroll
    for (int mi = 0; mi < 2; ++mi)
#pragma unroll
      for (int ks = 0; ks < 2; ++ks)
        ag[mi][ks] = *(const bf16x8*)(sa + aoff[2 + mi][ks]);
    if (pf) STAGE_B(s2, t + 2);
    if (pf)
      asm volatile("s_waitcnt vmcnt(6)" ::: "memory");
    else
      asm volatile("s_waitcnt vmcnt(0)" ::: "memory");
    __builtin_amdgcn_s_barrier();
    asm volatile("" ::: "memory");
    __builtin_amdgcn_s_setprio(1);
#pragma unroll
    for (int ni = 0; ni < 4; ++ni)
#pragma unroll
      for (int mi = 0; mi < 2; ++mi)
#pragma unroll
        for (int ks = 0; ks < 2; ++ks)
          acc[2 + mi][ni] = mfma32(ag[mi][ks], bfr[ni][ks], acc[2 + mi][ni]);
    __builtin_amdgcn_s_setprio(0);

    s0 += 1;
    if (s0 >= 3) s0 = 0;
  }

  // ---- epilogue ----
  if constexpr (EPI == 0) {
    float* C = (float*)O0;
#pragma unroll
    for (int mi = 0; mi < 4; ++mi)
#pragma unroll
      for (int ni = 0; ni < 4; ++ni)
#pragma unroll
        for (int r = 0; r < 4; ++r) {
          const int row = m0 + wrr * 64 + mi * 16 + hi * 4 + r;
          const int col = n0 + wcc * 64 + ni * 16 + lo;
          C[(size_t)row * 2048 + col] = acc[mi][ni][r];
        }
  } else if constexpr (EPI == 1) {
    const int qk = n0 >> 11;  // 0 = Q cols, 1 = K cols (block-uniform)
    bf16_t* Xh = (bf16_t*)(qk ? O2 : O0);
    bf16_t* Xl = (bf16_t*)(qk ? O3 : O1);
    const float scale = qk ? 1.0f : kQScale;
    const int is64 = (tokpos[1] == 0) ? 1 : 0;
#pragma unroll
    for (int mi = 0; mi < 4; ++mi) {
#pragma unroll
      for (int r = 0; r < 4; ++r) {
        const int row = m0 + wrr * 64 + mi * 16 + hi * 4 + r;
        const int pos = is64 ? tokpos[2 * row] : tokpos[row];
#pragma unroll
        for (int ni = 0; ni < 4; ++ni) {
          const int col = n0 + wcc * 64 + ni * 16 + lo;
          const float v = acc[mi][ni][r] * scale;
          const float pv = __shfl_xor(v, 1);  // paired column (col^1)
          const int ip = (col & 127) >> 1;
          const float c = cost[pos * 64 + ip];
          const float sn = sint[pos * 64 + ip];
          const float sgn = (lo & 1) ? sn : -sn;
          const float rv = v * c + pv * sgn;
          const bf16_t hb = (bf16_t)rv;
          const size_t o = (size_t)row * 2048 + (col & 2047);
          Xh[o] = hb;
          Xl[o] = (bf16_t)(rv - (float)hb);
        }
      }
    }
  } else {  // EPI == 2 : V^T per head [bh*128+d][s]
    bf16_t* VT = (bf16_t*)O0;
#pragma unroll
    for (int mi = 0; mi < 4; ++mi)
#pragma unroll
      for (int ni = 0; ni < 4; ++ni) {
        const int col = n0 + wcc * 64 + ni * 16 + lo;
        const int h = col >> 7, d = col & 127;
        const int rowb = m0 + wrr * 64 + mi * 16 + hi * 4;
        const int b = rowb >> 11, s = rowb & (kSeq - 1);
        bf16x4 ov;
#pragma unroll
        for (int r = 0; r < 4; ++r) ov[r] = (bf16_t)acc[mi][ni][r];
        *(bf16x4*)(VT + ((size_t)((b * kHeads + h) * kDk + d)) * kSeq + s) = ov;
      }
  }
}

// ---------------- Causal flash attention, strip-paired, 8 waves -------------
__global__ __launch_bounds__(512, 2) void k_attn4(
    const bf16_t* __restrict__ Qh, const bf16_t* __restrict__ Ql,
    const bf16_t* __restrict__ Kh, const bf16_t* __restrict__ Kl,
    const bf16_t* __restrict__ VT, bf16_t* __restrict__ Ob) {
  __shared__ __align__(16) bf16_t sK[2][2][64 * 128];
  __shared__ __align__(16) bf16_t sV[2][128 * 64];

  const int tid = threadIdx.x;
  const int wid = tid >> 6, lane = tid & 63;
  const int lo = lane & 15, hi = lane >> 4;
  const int flat = blockIdx.x;  // 256 blocks
  const int j = flat >> 3;
  const int bh = (flat & 7) * 4 + (j & 3);  // XCD x -> heads 4x..4x+3
  const int p = j >> 2;                     // 0..7
  const int b = bh >> 4, h = bh & 15;
  const int qiW = (wid < 4) ? (15 - p) : p;
  const int qw = qiW * 128 + (wid & 3) * 32;  // this wave's 32 q-rows
  const int nkv = 2 * (15 - p) + 2;           // 64-key tiles staged

  bf16x8 qhf[4][2], qlf[4][2];
  {
    const size_t qbase =
        (size_t)(b * kSeq + qw + lo) * kDModel + h * kDk + hi * 8;
#pragma unroll
    for (int qt = 0; qt < 2; ++qt)
#pragma unroll
      for (int ks = 0; ks < 4; ++ks) {
        const size_t o = qbase + (size_t)qt * 16 * kDModel + ks * 32;
        qhf[ks][qt] = *(const bf16x8*)(Qh + o);
        qlf[ks][qt] = *(const bf16x8*)(Ql + o);
      }
  }

  const int rK0 = wid * 8 + (lane >> 4);
  const int gK0 = ((lane & 15) ^ (rK0 & 15)) * 8;
  const int gK1 = ((lane & 15) ^ ((rK0 + 4) & 15)) * 8;
  const bf16_t* pKh0 = Kh + (size_t)(b * kSeq + rK0) * kDModel + h * kDk + gK0;
  const bf16_t* pKh1 = Kh + (size_t)(b * kSeq + rK0 + 4) * kDModel + h * kDk + gK1;
  const bf16_t* pKl0 = Kl + (pKh0 - Kh);
  const bf16_t* pKl1 = Kl + (pKh1 - Kh);
  const int dV0 = wid * 16 + (lane >> 3);
  const int gV0 = ((lane & 7) ^ (dV0 & 7)) * 8;
  const int gV1 = ((lane & 7) ^ ((dV0 + 8) & 7)) * 8;
  const bf16_t* pV0 = VT + (size_t)(bh * kDk + dV0) * kSeq + gV0;
  const bf16_t* pV1 = VT + (size_t)(bh * kDk + dV0 + 8) * kSeq + gV1;
  const int ldsK = (wid * 8) * 128;
  const int ldsV = (wid * 16) * 64;

  f32x4 of[8][2];
  const f32x4 z = {0.f, 0.f, 0.f, 0.f};
#pragma unroll
  for (int di = 0; di < 8; ++di) {
    of[di][0] = z;
    of[di][1] = z;
  }
  float m[2] = {-3e38f, -3e38f};
  float l[2] = {0.f, 0.f};

  auto STAGE = [&](int buf, int t) {
    const size_t ko = (size_t)t * 64 * kDModel;
    const size_t vo = (size_t)t * 64;
    bf16_t* dk = sK[buf][0] + ldsK;
    bf16_t* dl = sK[buf][1] + ldsK;
    gload_lds16(pKh0 + ko, dk);
    gload_lds16(pKh1 + ko, dk + 512);
    gload_lds16(pKl0 + ko, dl);
    gload_lds16(pKl1 + ko, dl + 512);
    bf16_t* dv = sV[buf] + ldsV;
    gload_lds16(pV0 + vo, dv);
    gload_lds16(pV1 + vo, dv + 512);
  };

  STAGE(0, 0);
  __syncthreads();

  for (int t = 0; t < nkv; ++t) {
    const int kv0 = t * 64;
    if (t + 1 < nkv) STAGE((t + 1) & 1, t + 1);

    if (kv0 <= qw + 31) {
      const bf16_t* bKh = sK[t & 1][0];
      const bf16_t* bKl = sK[t & 1][1];
      const bf16_t* bV = sV[t & 1];
      const bool maskedw = (kv0 + 63 > qw);

      f32x4 st[4][2];
#pragma unroll
      for (int kt = 0; kt < 4; ++kt) {
        st[kt][0] = z;
        st[kt][1] = z;
      }
#pragma unroll
      for (int kt = 0; kt < 4; ++kt) {
#pragma unroll
        for (int ks = 0; ks < 4; ++ks) {
          const int krow = kt * 16 + lo;
          const int ka = krow * 128 + (((ks * 4 + hi) ^ (krow & 15)) * 8);
          const bf16x8 kh8 = *(const bf16x8*)(bKh + ka);
          const bf16x8 kl8 = *(const bf16x8*)(bKl + ka);
#pragma unroll
          for (int qt = 0; qt < 2; ++qt) {
            st[kt][qt] = mfma32(kh8, qhf[ks][qt], st[kt][qt]);
            st[kt][qt] = mfma32(kh8, qlf[ks][qt], st[kt][qt]);
            st[kt][qt] = mfma32(kl8, qhf[ks][qt], st[kt][qt]);
          }
        }
      }

      bf16x4 pb[4][2];
#pragma unroll
      for (int qt = 0; qt < 2; ++qt) {
        const int q = qw + qt * 16 + lo;
        float mt = -3e38f;
#pragma unroll
        for (int kt = 0; kt < 4; ++kt)
#pragma unroll
          for (int r = 0; r < 4; ++r) {
            float s = st[kt][qt][r];
            if (maskedw && (kv0 + kt * 16 + hi * 4 + r > q)) s = -1e30f;
            st[kt][qt][r] = s;
            mt = fmaxf(mt, s);
          }
        mt = fmaxf(mt, __shfl_xor(mt, 16));
        mt = fmaxf(mt, __shfl_xor(mt, 32));
        if (!__all(mt <= m[qt] + 8.f)) {
          const float mnew = fmaxf(m[qt], mt);
          const float corr = __expf(m[qt] - mnew);
          l[qt] *= corr;
#pragma unroll
          for (int di = 0; di < 8; ++di) of[di][qt] = of[di][qt] * corr;
          m[qt] = mnew;
        }
        float rs = 0.f;
#pragma unroll
        for (int kt = 0; kt < 4; ++kt) {
          bf16x4 pv;
#pragma unroll
          for (int r = 0; r < 4; ++r) {
            const float pp = __expf(st[kt][qt][r] - m[qt]);
            rs += pp;
            pv[r] = (bf16_t)pp;
          }
          pb[kt][qt] = pv;
        }
        rs += __shfl_xor(rs, 16);
        rs += __shfl_xor(rs, 32);
        l[qt] += rs;
      }

#pragma unroll
      for (int di = 0; di < 8; ++di) {
        const int d = di * 16 + lo;
#pragma unroll
        for (int kt = 0; kt < 4; ++kt) {
          const int va =
              d * 64 + (((kt * 2 + (hi >> 1)) ^ (d & 7)) * 8) + (hi & 1) * 4;
          const bf16x4 vf = *(const bf16x4*)(bV + va);
          of[di][0] = mfma16(vf, pb[kt][0], of[di][0]);
          of[di][1] = mfma16(vf, pb[kt][1], of[di][1]);
        }
      }
    }
    __syncthreads();
  }

#pragma unroll
  for (int qt = 0; qt < 2; ++qt) {
    const float linv = 1.f / l[qt];
    const size_t ob =
        (size_t)(b * kSeq + qw + qt * 16 + lo) * kDModel + h * kDk + hi * 4;
#pragma unroll
    for (int di = 0; di < 8; ++di) {
      bf16x4 ov;
#pragma unroll
      for (int r = 0; r < 4; ++r) ov[r] = (bf16_t)(of[di][qt][r] * linv);
      *(bf16x4*)(Ob + ob + di * 16) = ov;
    }
  }
}

}  // namespace

extern "C" void kernel_launch(void* const* d_in, const int* in_sizes, int n_in,
                              void* d_out, int out_size, void* d_ws, size_t ws_size,
                              hipStream_t stream) {
  (void)in_sizes; (void)n_in; (void)out_size;
  const float* x = (const float*)d_in[0];
  const int* tokpos = (const int*)d_in[1];
  const float* wq = (const float*)d_in[2];
  const float* wk = (const float*)d_in[3];
  const float* wv = (const float*)d_in[4];
  const float* wo = (const float*)d_in[5];
  float* out = (float*)d_out;

  char* p = (char*)d_ws;
  auto take = [&](size_t bytes) { char* q = p; p += bytes; return q; };
  float* cost = (float*)take((size_t)kSeq * 64 * sizeof(float));
  float* sint = (float*)take((size_t)kSeq * 64 * sizeof(float));
  const size_t mat = (size_t)kM * kDModel * sizeof(bf16_t);        // 16.8 MB
  const size_t wmat = (size_t)kDModel * kDModel * sizeof(bf16_t);  // 8.4 MB
  bf16_t* xh = (bf16_t*)take(mat);
  bf16_t* xl = (bf16_t*)take(mat);
  bf16_t* wqkth = (bf16_t*)take(2 * wmat);  // rows [0,2048)=wq^T, [2048,4096)=wk^T
  bf16_t* wqktl = (bf16_t*)take(2 * wmat);
  bf16_t* wvt = (bf16_t*)take(wmat);
  bf16_t* wot = (bf16_t*)take(wmat);
  bf16_t* qh = (bf16_t*)take(mat);
  bf16_t* ql = (bf16_t*)take(mat);
  bf16_t* kh = (bf16_t*)take(mat);
  bf16_t* kl = (bf16_t*)take(mat);
  bf16_t* vt = (bf16_t*)take(mat);
  bf16_t* ob = (bf16_t*)take(mat);
  if ((size_t)(p - (char*)d_ws) > ws_size) {
    fprintf(stderr, "MHA: workspace too small: need %zu have %zu\n",
            (size_t)(p - (char*)d_ws), ws_size);
    return;
  }

  k_rope_table<<<dim3(kSeq), dim3(64), 0, stream>>>(cost, sint);
  k_split_x<<<dim3((kM * kDModel) / (256 * 4)), dim3(256), 0, stream>>>(
      x, xh, xl, kM * kDModel);
  {
    dim3 tb(32, 8), tg(kDModel / 32, kDModel / 32);
    k_transpose_w<<<tg, tb, 0, stream>>>(wq, wqkth, wqktl);
    k_transpose_w<<<tg, tb, 0, stream>>>(wk, wqkth + (size_t)2048 * 2048,
                                         wqktl + (size_t)2048 * 2048);
    k_transpose_w<<<tg, tb, 0, stream>>>(wv, wvt, nullptr);
    k_transpose_w<<<tg, tb, 0, stream>>>(wo, wot, nullptr);
  }
  // Fused Q|K projection + RoPE: M=4096, N=4096, K'=3*2048 (96 tiles)
  k_gemm8<3, 1><<<dim3(512), dim3(512), 0, stream>>>(
      xh, xl, wqkth, wqktl, qh, ql, kh, kl, tokpos, cost, sint, 32, 96);
  // V projection -> V^T: M=4096, N=2048, K=2048 (32 tiles)
  k_gemm8<1, 2><<<dim3(256), dim3(512), 0, stream>>>(
      xh, nullptr, wvt, nullptr, vt, nullptr, nullptr, nullptr, nullptr,
      nullptr, nullptr, 16, 32);
  k_attn4<<<dim3(256), dim3(512), 0, stream>>>(qh, ql, kh, kl, vt, ob);
  // Output projection: fp32 out
  k_gemm8<1, 0><<<dim3(256), dim3(512), 0, stream>>>(
      ob, nullptr, wot, nullptr, out, nullptr, nullptr, nullptr, nullptr,
      nullptr, nullptr, 16, 32);
}